// Round 17
// baseline (284.427 us; speedup 1.0000x reference)
//
#include <hip/hip_runtime.h>
#include <hip/hip_bf16.h>

#define NN 30000
#define EE 480000

typedef __attribute__((ext_vector_type(8))) short short8;
typedef __attribute__((ext_vector_type(4))) short short4v;
typedef __attribute__((ext_vector_type(4))) float floatx4;
typedef unsigned short u16;

__device__ __forceinline__ u16 f2bf(float f) {
  union { float f; unsigned u; } v; v.f = f;
  unsigned u = v.u;
  u += 0x7FFFu + ((u >> 16) & 1u);  // RNE
  return (u16)(u >> 16);
}
__device__ __forceinline__ float bf2f(u16 u) {
  union { unsigned u; float f; } v; v.u = ((unsigned)u) << 16;
  return v.f;
}
__device__ __forceinline__ float bflo(unsigned u) {
  union { unsigned x; float f; } v; v.x = u << 16; return v.f;
}
__device__ __forceinline__ float bfhi(unsigned u) {
  union { unsigned x; float f; } v; v.x = u & 0xFFFF0000u; return v.f;
}
__device__ __forceinline__ unsigned packbf(float a, float b) {
  return (unsigned)f2bf(a) | ((unsigned)f2bf(b) << 16);
}
__device__ __forceinline__ short8 pack8(float4 A, float4 B) {
  union { unsigned u[4]; short8 s; } r;
  r.u[0] = packbf(A.x, A.y);
  r.u[1] = packbf(A.z, A.w);
  r.u[2] = packbf(B.x, B.y);
  r.u[3] = packbf(B.z, B.w);
  return r.s;
}

// ---- DPP cross-lane adds (VALU pipe, no LDS) ----
template <int CTRL>
__device__ __forceinline__ float dppadd(float v) {
  int s = __builtin_amdgcn_update_dpp(0, __builtin_bit_cast(int, v), CTRL, 0xF, 0xF, true);
  return v + __builtin_bit_cast(float, s);
}
__device__ __forceinline__ float rowsum16(float v) {
  v = dppadd<0x121>(v); v = dppadd<0x122>(v); v = dppadd<0x124>(v); v = dppadd<0x128>(v);
  return v;
}
__device__ __forceinline__ float rowsum8(float v) {
  v = dppadd<0xB1>(v); v = dppadd<0x4E>(v); v = dppadd<0x141>(v);
  return v;
}

#define MFMA32 __builtin_amdgcn_mfma_f32_16x16x32_bf16

#if __has_builtin(__builtin_amdgcn_mfma_f32_16x16x16bf16_1k)
__device__ __forceinline__ floatx4 MFMA16(short4v a, short4v b, floatx4 c) {
  return __builtin_amdgcn_mfma_f32_16x16x16bf16_1k(a, b, c, 0, 0, 0);
}
#else
__device__ __forceinline__ floatx4 MFMA16(short4v a, short4v b, floatx4 c) {
  asm volatile("v_mfma_f32_16x16x16_bf16 %0, %1, %2, %0"
               : "+v"(c) : "v"(a), "v"(b));
  return c;
}
#endif

// ---------------------------------------------------------------------------
// k_fuse: fusedW = mha_out_w @ w_nei ; fusedB = b_in + b_nei + mha_out_b @ w_nei
// ---------------------------------------------------------------------------
__global__ __launch_bounds__(128) void k_fuse(
    const float* __restrict__ out_w, const float* __restrict__ out_b,
    const float* __restrict__ w_nei, const float* __restrict__ b_nei,
    const float* __restrict__ b_in,
    float* __restrict__ fusedW, float* __restrict__ fusedB) {
  int i = blockIdx.x, j = threadIdx.x;
  if (i < 64) {
    float a = 0.f;
    for (int kk = 0; kk < 64; ++kk) a = fmaf(out_w[i * 64 + kk], w_nei[kk * 128 + j], a);
    fusedW[i * 128 + j] = a;
  } else {
    float a = b_in[j] + b_nei[j];
    for (int kk = 0; kk < 64; ++kk) a = fmaf(out_b[kk], w_nei[kk * 128 + j], a);
    fusedB[j] = a;
  }
}

// merged: blocks 0-255 -> G rows; block 256 -> fusedB2
__global__ __launch_bounds__(128) void k_prepB(
    const float* __restrict__ in_w, const float* __restrict__ fusedW,
    const float* __restrict__ fusedB, const float* __restrict__ in_b,
    float* __restrict__ G, float* __restrict__ fusedB2) {
  int bx = blockIdx.x, c = threadIdx.x;
  if (bx < 256) {
    int h = bx >> 6, d = bx & 63;
    float a = 0.f;
    for (int dd = 0; dd < 16; ++dd)
      a = fmaf(in_w[d * 192 + 128 + h * 16 + dd], fusedW[(h * 16 + dd) * 128 + c], a);
    G[bx * 128 + c] = a;
  } else {
    float a = fusedB[c];
    for (int d = 0; d < 64; ++d) a = fmaf(in_b[128 + d], fusedW[d * 128 + c], a);
    fusedB2[c] = a;
  }
}

// merged: blocks 0-127 -> wtP2; 128-895 -> wt3; 896-959 -> wtQK
__global__ __launch_bounds__(128) void k_prep2(
    const float* __restrict__ w_in, const float* __restrict__ G,
    const float* __restrict__ wq, const float* __restrict__ wk,
    const float* __restrict__ wv, const float* __restrict__ in_w,
    u16* __restrict__ wtP2, u16* __restrict__ wt3, u16* __restrict__ wtQK) {
  int bx = blockIdx.x, t = threadIdx.x;
  if (bx < 128) {
    int c = bx;
#pragma unroll
    for (int part = 0; part < 3; ++part) {
      int k = part * 128 + t;
      float v = (k < 128) ? w_in[(size_t)k * 128 + c] : G[(size_t)(k - 128) * 128 + c];
      wtP2[(size_t)c * 384 + k] = f2bf(v);
    }
  } else if (bx < 896) {
    int b2 = bx - 128;
    int l = b2 / 384, rem = b2 % 384, o = rem >> 7, c = rem & 127;
    const float* w = (o == 0 ? wq : (o == 1 ? wk : wv)) + (size_t)l * 16384;
    wt3[(size_t)b2 * 128 + t] = f2bf(w[(size_t)t * 128 + c]);
  } else {
    int c = (bx - 896) * 2 + (t >> 6), kk = t & 63;
    float s = (c < 64) ? 0.25f : 1.f;
    wtQK[(size_t)c * 64 + kk] = f2bf(s * in_w[(size_t)kk * 192 + c]);
  }
}

// ---------------------------------------------------------------------------
// k_mha9: fused QK-GEMM + per-node attention colsums + Y (round-13 version).
// ---------------------------------------------------------------------------
__global__ __launch_bounds__(512) void k_mha9(
    const float* __restrict__ xn,    // nei_features [300000,64] f32
    const u16* __restrict__ wtQK,    // [128][64] bf16
    const float* __restrict__ in_b,  // [192]
    u16* __restrict__ Yb) {          // [NN,256]
  __shared__ unsigned qks[80 * 66];
  __shared__ float cs_lds[8][4][12];
  int t = threadIdx.x, w = t >> 6, l = t & 63;
  int lr = l & 15, lq = l >> 4;
  const floatx4 zf = {0.f, 0.f, 0.f, 0.f};
  size_t r0 = (size_t)blockIdx.x * 80;

  if (w < 5) {
    int row = w * 16 + lr;
    size_t arow = r0 + row;
    const float* xp = xn + arow * 64 + lq * 8;
    float4 f0 = *(const float4*)xp;
    float4 f1 = *(const float4*)(xp + 4);
    float4 f2 = *(const float4*)(xp + 32);
    float4 f3 = *(const float4*)(xp + 36);
    short8 a0 = pack8(f0, f1), a1 = pack8(f2, f3);
    floatx4 acc[8];
#pragma unroll
    for (int ct = 0; ct < 8; ++ct) acc[ct] = zf;
#pragma unroll
    for (int ct = 0; ct < 8; ++ct) {
      const short8* bp = (const short8*)(wtQK + (size_t)(ct * 16 + lr) * 64);
      acc[ct] = MFMA32(a0, bp[lq], acc[ct], 0, 0, 0);
      acc[ct] = MFMA32(a1, bp[4 + lq], acc[ct], 0, 0, 0);
    }
#pragma unroll
    for (int ct = 0; ct < 4; ++ct) {
      float bq_ = in_b[ct * 16 + lr] * 0.25f;
      float bk_ = in_b[64 + ct * 16 + lr];
#pragma unroll
      for (int r = 0; r < 4; ++r)
        qks[(w * 16 + lq * 4 + r) * 66 + ct * 16 + lr] =
            packbf(acc[ct][r] + bq_, acc[ct + 4][r] + bk_);
    }
  }
  __syncthreads();

  int seqc = lr < 10 ? lr : 9;
  {
#pragma unroll
    for (int h = 0; h < 4; ++h) {
      const unsigned* rp = &qks[(w * 10 + seqc) * 66 + h * 16 + lq * 4];
      uint2 u0 = *(const uint2*)rp;
      uint2 u1 = *(const uint2*)(rp + 2);
      union { unsigned u[2]; short4v s; } qv, kv;
      qv.u[0] = (u0.x & 0xFFFFu) | (u0.y << 16);
      qv.u[1] = (u1.x & 0xFFFFu) | (u1.y << 16);
      kv.u[0] = (u0.x >> 16) | (u0.y & 0xFFFF0000u);
      kv.u[1] = (u1.x >> 16) | (u1.y & 0xFFFF0000u);
      floatx4 s4 = MFMA16(kv.s, qv.s, zf);   // S^T[j=lq*4+r][i=lr]
      int j0 = lq * 4;
      float e0 = (j0 + 0 < 10) ? __expf(s4[0]) : 0.f;
      float e1 = (j0 + 1 < 10) ? __expf(s4[1]) : 0.f;
      float e2 = (j0 + 2 < 10) ? __expf(s4[2]) : 0.f;
      float e3 = (j0 + 3 < 10) ? __expf(s4[3]) : 0.f;
      float den = e0 + e1 + e2 + e3;
      den += __shfl_xor(den, 16, 64);
      den += __shfl_xor(den, 32, 64);
      float rden = 0.1f / den;  // fold seq-mean 1/10
      float v0 = (lr < 10) ? e0 * rden : 0.f;
      float v1 = (lr < 10) ? e1 * rden : 0.f;
      float v2 = (lr < 10) ? e2 * rden : 0.f;
      float v3 = (lr < 10) ? e3 * rden : 0.f;
      v0 = rowsum16(v0);
      v1 = rowsum16(v1);
      v2 = rowsum16(v2);
      v3 = rowsum16(v3);
      if (lr == 0) {
        cs_lds[w][h][lq * 4 + 0] = v0;
        cs_lds[w][h][lq * 4 + 1] = v1;
        cs_lds[w][h][lq * 4 + 2] = v2;
        cs_lds[w][h][lq * 4 + 3] = v3;
      }
    }
    size_t node = (size_t)blockIdx.x * 8 + w;
    const float* xp2 = xn + node * 640 + l;  // lane l = dim d
    float y0 = 0.f, y1 = 0.f, y2 = 0.f, y3 = 0.f;
#pragma unroll
    for (int j = 0; j < 10; ++j) {
      float xv = xp2[j * 64];                // coalesced 256B, cache-warm
      y0 = fmaf(cs_lds[w][0][j], xv, y0);
      y1 = fmaf(cs_lds[w][1][j], xv, y1);
      y2 = fmaf(cs_lds[w][2][j], xv, y2);
      y3 = fmaf(cs_lds[w][3][j], xv, y3);
    }
    size_t yb = node * 256;
    Yb[yb + l] = f2bf(y0);
    Yb[yb + 64 + l] = f2bf(y1);
    Yb[yb + 128 + l] = f2bf(y2);
    Yb[yb + 192 + l] = f2bf(y3);
  }
}

// ---------------------------------------------------------------------------
// k_projqkv3: 32 rows/block, 512 thr, grid 938 -> 7504 waves (2x TLP).
// Phase A: wave (wr=w&1, q4=w>>1): rows wr*16, cols q4*32 (2 ct x 12 kb).
// Phase B: wave: rows wr*16, 3 col-pairs (pg = q4*3+p).
// ---------------------------------------------------------------------------
__global__ __launch_bounds__(512) void k_projqkv3(
    const float* __restrict__ x, const u16* __restrict__ Yb,
    const u16* __restrict__ wtP2, const float* __restrict__ fusedB2,
    const u16* __restrict__ wt3l,
    const float* __restrict__ bqL, const float* __restrict__ bkL,
    const float* __restrict__ bvL,
    unsigned* __restrict__ q2, unsigned* __restrict__ k2, unsigned* __restrict__ v2) {
  __shared__ u16 hs[32 * 128];
  int t = threadIdx.x, w = t >> 6, l = t & 63, lr = l & 15, lq = l >> 4;
  int wr = w & 1, q4 = w >> 1;
  int row0 = blockIdx.x * 32 + wr * 16;
  int arow = row0 + lr; if (arow >= NN) arow = NN - 1;
  // ---- phase A ----
  {
    const float* xp = x + (size_t)arow * 128;
    const short8* yp = (const short8*)(Yb + (size_t)arow * 256);
    short8 afr[12];
#pragma unroll
    for (int kb = 0; kb < 4; ++kb) {
      float4 fa = *(const float4*)(xp + kb * 32 + lq * 8);
      float4 fb = *(const float4*)(xp + kb * 32 + lq * 8 + 4);
      afr[kb] = pack8(fa, fb);
    }
#pragma unroll
    for (int m = 0; m < 8; ++m) afr[4 + m] = yp[m * 4 + lq];
    floatx4 acc[2];
    acc[0] = (floatx4){0.f, 0.f, 0.f, 0.f};
    acc[1] = (floatx4){0.f, 0.f, 0.f, 0.f};
#pragma unroll
    for (int ct = 0; ct < 2; ++ct) {
      int ctg = q4 * 2 + ct;
      const short8* bp = (const short8*)(wtP2 + (size_t)(ctg * 16 + lr) * 384);
#pragma unroll
      for (int kb = 0; kb < 12; ++kb)
        acc[ct] = MFMA32(afr[kb], bp[kb * 4 + lq], acc[ct], 0, 0, 0);
    }
#pragma unroll
    for (int ct = 0; ct < 2; ++ct) {
      int ctg = q4 * 2 + ct;
      int col = ctg * 16 + lr;
      float bias = fusedB2[col];
#pragma unroll
      for (int r = 0; r < 4; ++r)
        hs[(wr * 16 + lq * 4 + r) * 128 + col] = f2bf(acc[ct][r] + bias);
    }
  }
  __syncthreads();
  // ---- phase B: 3 col-pairs per wave ----
  {
    int lrow = wr * 16 + lr;
    const short8* ap = (const short8*)(hs + lrow * 128);
    short8 a0 = ap[lq], a1 = ap[4 + lq], a2 = ap[8 + lq], a3 = ap[12 + lq];
    const short8* wt8 = (const short8*)wt3l;
    floatx4 accL[3], accH[3];
#pragma unroll
    for (int p = 0; p < 3; ++p) {
      accL[p] = (floatx4){0.f, 0.f, 0.f, 0.f};
      accH[p] = (floatx4){0.f, 0.f, 0.f, 0.f};
    }
#pragma unroll
    for (int p = 0; p < 3; ++p) {
      int pg = q4 * 3 + p;
      int o = pg >> 2, cc = pg & 3;
      const short8* bpL = wt8 + (size_t)(o * 128 + cc * 16 + lr) * 16;
      const short8* bpH = wt8 + (size_t)(o * 128 + (cc + 4) * 16 + lr) * 16;
      accL[p] = MFMA32(a0, bpL[lq], accL[p], 0, 0, 0);
      accL[p] = MFMA32(a1, bpL[4 + lq], accL[p], 0, 0, 0);
      accL[p] = MFMA32(a2, bpL[8 + lq], accL[p], 0, 0, 0);
      accL[p] = MFMA32(a3, bpL[12 + lq], accL[p], 0, 0, 0);
      accH[p] = MFMA32(a0, bpH[lq], accH[p], 0, 0, 0);
      accH[p] = MFMA32(a1, bpH[4 + lq], accH[p], 0, 0, 0);
      accH[p] = MFMA32(a2, bpH[8 + lq], accH[p], 0, 0, 0);
      accH[p] = MFMA32(a3, bpH[12 + lq], accH[p], 0, 0, 0);
    }
#pragma unroll
    for (int p = 0; p < 3; ++p) {
      int pg = q4 * 3 + p;
      int o = pg >> 2, cc = pg & 3;
      unsigned* op = o == 0 ? q2 : (o == 1 ? k2 : v2);
      const float* bp2 = o == 0 ? bqL : (o == 1 ? bkL : bvL);
      int col = cc * 16 + lr;
      float blo = bp2[col], bhi = bp2[64 + col];
#pragma unroll
      for (int r = 0; r < 4; ++r) {
        int row = row0 + lq * 4 + r;
        if (row < NN)
          op[(size_t)row * 64 + col] = packbf(accL[p][r] + blo, accH[p][r] + bhi);
      }
    }
  }
}

// ---------------------------------------------------------------------------
// k_qkv4c: 32 rows/block, 512 thr, grid 938; wave (wr,q4) does 3 col-pairs.
// ---------------------------------------------------------------------------
__global__ __launch_bounds__(512) void k_qkv4c(
    const u16* __restrict__ hb, const u16* __restrict__ wt3l,
    const float* __restrict__ bqL, const float* __restrict__ bkL,
    const float* __restrict__ bvL,
    unsigned* __restrict__ q2, unsigned* __restrict__ k2, unsigned* __restrict__ v2) {
  int t = threadIdx.x, w = t >> 6, l = t & 63, lr = l & 15, lq = l >> 4;
  int wr = w & 1, q4 = w >> 1;
  int row0 = blockIdx.x * 32 + wr * 16;
  int arow = row0 + lr; if (arow >= NN) arow = NN - 1;
  const short8* ap = (const short8*)(hb + (size_t)arow * 128);
  short8 a0 = ap[lq], a1 = ap[4 + lq], a2 = ap[8 + lq], a3 = ap[12 + lq];
  const short8* wt8 = (const short8*)wt3l;
  floatx4 accL[3], accH[3];
#pragma unroll
  for (int p = 0; p < 3; ++p) {
    accL[p] = (floatx4){0.f, 0.f, 0.f, 0.f};
    accH[p] = (floatx4){0.f, 0.f, 0.f, 0.f};
  }
#pragma unroll
  for (int p = 0; p < 3; ++p) {
    int pg = q4 * 3 + p;
    int o = pg >> 2, cc = pg & 3;
    const short8* bpL = wt8 + (size_t)(o * 128 + cc * 16 + lr) * 16;
    const short8* bpH = wt8 + (size_t)(o * 128 + (cc + 4) * 16 + lr) * 16;
    accL[p] = MFMA32(a0, bpL[lq], accL[p], 0, 0, 0);
    accL[p] = MFMA32(a1, bpL[4 + lq], accL[p], 0, 0, 0);
    accL[p] = MFMA32(a2, bpL[8 + lq], accL[p], 0, 0, 0);
    accL[p] = MFMA32(a3, bpL[12 + lq], accL[p], 0, 0, 0);
    accH[p] = MFMA32(a0, bpH[lq], accH[p], 0, 0, 0);
    accH[p] = MFMA32(a1, bpH[4 + lq], accH[p], 0, 0, 0);
    accH[p] = MFMA32(a2, bpH[8 + lq], accH[p], 0, 0, 0);
    accH[p] = MFMA32(a3, bpH[12 + lq], accH[p], 0, 0, 0);
  }
#pragma unroll
  for (int p = 0; p < 3; ++p) {
    int pg = q4 * 3 + p;
    int o = pg >> 2, cc = pg & 3;
    unsigned* op = o == 0 ? q2 : (o == 1 ? k2 : v2);
    const float* bp2 = o == 0 ? bqL : (o == 1 ? bkL : bvL);
    int col = cc * 16 + lr;
    float blo = bp2[col], bhi = bp2[64 + col];
#pragma unroll
    for (int r = 0; r < 4; ++r) {
      int row = row0 + lq * 4 + r;
      if (row < NN)
        op[(size_t)row * 64 + col] = packbf(accL[p][r] + blo, accH[p][r] + bhi);
    }
  }
}

// ---------------------------------------------------------------------------
// k_fill2: XCD-sliced bucketed adjacency.
// ---------------------------------------------------------------------------
#define FILLB 469
__global__ __launch_bounds__(256) void k_fill2(const int* __restrict__ ei,
                                               int* __restrict__ cnt,
                                               int* __restrict__ esrc) {
  int bx = blockIdx.x;
  int grp = bx & 7, bi = bx >> 3;
  int lo = grp * (NN / 8), hi = lo + (NN / 8);
  int tid = bi * 256 + threadIdx.x;
#pragma unroll
  for (int it = 0; it < 8; ++it) {
    int e = tid + it * (FILLB * 256);
    if (e < 2 * EE) {
      int l = e >= EE;
      int ee = e - l * EE;
      int d = ei[(size_t)(2 * l + 1) * EE + ee];
      if (d >= lo && d < hi) {
        int s = ei[(size_t)(2 * l) * EE + ee];
        int c = atomicAdd(&cnt[l * NN + d], 1);
        if (c < 64) esrc[((size_t)l * NN + d) * 64 + c] = s;
      }
    }
  }
}

// ---------------------------------------------------------------------------
// k_sagg7: fused edge-score + segment-softmax (no max) + PV + ReLU + LN.
// ---------------------------------------------------------------------------
__global__ __launch_bounds__(256) void k_sagg7(
    const unsigned* __restrict__ q2, const unsigned* __restrict__ k2,
    const unsigned* __restrict__ v2, const int* __restrict__ esrc,
    const int* __restrict__ cnt, const float* __restrict__ g,
    const float* __restrict__ bb, u16* __restrict__ hb,
    const float* __restrict__ wo, const float* __restrict__ bo,
    float* __restrict__ outp) {
  const float SC = 0.17677669529663687f;
  int t = threadIdx.x, w = t >> 6, l = t & 63;
  int e = l >> 4, dd = l & 15;
  int n = blockIdx.x * 4 + w;
  int deg = cnt[n]; if (deg > 64) deg = 64;
  const int* sp = esrc + (size_t)n * 64;
  uint4 qp = *(const uint4*)(q2 + (size_t)n * 64 + dd * 4);
  float ql0 = bflo(qp.x), ql1 = bflo(qp.y), ql2 = bflo(qp.z), ql3 = bflo(qp.w);
  float qh0 = bfhi(qp.x), qh1 = bfhi(qp.y), qh2 = bfhi(qp.z), qh3 = bfhi(qp.w);
  float dA0 = 0.f, dA1 = 0.f, dB0 = 0.f, dB1 = 0.f;
  float alA0 = 0.f, alA1 = 0.f, alA2 = 0.f, alA3 = 0.f;
  float ahA0 = 0.f, ahA1 = 0.f, ahA2 = 0.f, ahA3 = 0.f;
  float alB0 = 0.f, alB1 = 0.f, alB2 = 0.f, alB3 = 0.f;
  float ahB0 = 0.f, ahB1 = 0.f, ahB2 = 0.f, ahB3 = 0.f;
  uint4 kA = {0, 0, 0, 0}, vA = {0, 0, 0, 0};
  uint4 kB = {0, 0, 0, 0}, vB = {0, 0, 0, 0};
  bool mA = false, mB = false;
  if (deg > 0) {
    int iA = e < deg ? e : deg - 1;           mA = e < deg;
    int iB = 4 + e < deg ? 4 + e : deg - 1;   mB = 4 + e < deg;
    int sA = sp[iA], sB = sp[iB];
    kA = *(const uint4*)(k2 + (size_t)sA * 64 + dd * 4);
    vA = *(const uint4*)(v2 + (size_t)sA * 64 + dd * 4);
    kB = *(const uint4*)(k2 + (size_t)sB * 64 + dd * 4);
    vB = *(const uint4*)(v2 + (size_t)sB * 64 + dd * 4);
  }
  for (int base = 0; base < deg; base += 8) {
    uint4 kAn = {0, 0, 0, 0}, vAn = {0, 0, 0, 0};
    uint4 kBn = {0, 0, 0, 0}, vBn = {0, 0, 0, 0};
    bool mAn = false, mBn = false;
    int nb = base + 8;
    if (nb < deg) {
      int iA = nb + e < deg ? nb + e : deg - 1;         mAn = nb + e < deg;
      int iB = nb + 4 + e < deg ? nb + 4 + e : deg - 1; mBn = nb + 4 + e < deg;
      int sA = sp[iA], sB = sp[iB];
      kAn = *(const uint4*)(k2 + (size_t)sA * 64 + dd * 4);
      vAn = *(const uint4*)(v2 + (size_t)sA * 64 + dd * 4);
      kBn = *(const uint4*)(k2 + (size_t)sB * 64 + dd * 4);
      vBn = *(const uint4*)(v2 + (size_t)sB * 64 + dd * 4);
    }
    float rA0 = ql0 * bflo(kA.x) + ql1 * bflo(kA.y) + ql2 * bflo(kA.z) + ql3 * bflo(kA.w);
    float rA1 = qh0 * bfhi(kA.x) + qh1 * bfhi(kA.y) + qh2 * bfhi(kA.z) + qh3 * bfhi(kA.w);
    float rB0 = ql0 * bflo(kB.x) + ql1 * bflo(kB.y) + ql2 * bflo(kB.z) + ql3 * bflo(kB.w);
    float rB1 = qh0 * bfhi(kB.x) + qh1 * bfhi(kB.y) + qh2 * bfhi(kB.z) + qh3 * bfhi(kB.w);
    rA0 = rowsum8(rA0); rA1 = rowsum8(rA1);
    rB0 = rowsum8(rB0); rB1 = rowsum8(rB1);
    float pA0 = mA ? __expf(rA0 * SC) : 0.f;
    float pA1 = mA ? __expf(rA1 * SC) : 0.f;
    float pB0 = mB ? __expf(rB0 * SC) : 0.f;
    float pB1 = mB ? __expf(rB1 * SC) : 0.f;
    dA0 += pA0; dA1 += pA1; dB0 += pB0; dB1 += pB1;
    alA0 = fmaf(pA0, bflo(vA.x), alA0); alA1 = fmaf(pA0, bflo(vA.y), alA1);
    alA2 = fmaf(pA0, bflo(vA.z), alA2); alA3 = fmaf(pA0, bflo(vA.w), alA3);
    ahA0 = fmaf(pA1, bfhi(vA.x), ahA0); ahA1 = fmaf(pA1, bfhi(vA.y), ahA1);
    ahA2 = fmaf(pA1, bfhi(vA.z), ahA2); ahA3 = fmaf(pA1, bfhi(vA.w), ahA3);
    alB0 = fmaf(pB0, bflo(vB.x), alB0); alB1 = fmaf(pB0, bflo(vB.y), alB1);
    alB2 = fmaf(pB0, bflo(vB.z), alB2); alB3 = fmaf(pB0, bflo(vB.w), alB3);
    ahB0 = fmaf(pB1, bfhi(vB.x), ahB0); ahB1 = fmaf(pB1, bfhi(vB.y), ahB1);
    ahB2 = fmaf(pB1, bfhi(vB.z), ahB2); ahB3 = fmaf(pB1, bfhi(vB.w), ahB3);
    kA = kAn; vA = vAn; mA = mAn;
    kB = kBn; vB = vBn; mB = mBn;
  }
  float d0 = dA0 + dB0, d1 = dA1 + dB1;
  float al0 = alA0 + alB0, al1 = alA1 + alB1, al2 = alA2 + alB2, al3 = alA3 + alB3;
  float ah0 = ahA0 + ahB0, ah1 = ahA1 + ahB1, ah2 = ahA2 + ahB2, ah3 = ahA3 + ahB3;
  d0 += __shfl_xor(d0, 16, 64); d0 += __shfl_xor(d0, 32, 64);
  d1 += __shfl_xor(d1, 16, 64); d1 += __shfl_xor(d1, 32, 64);
  al0 += __shfl_xor(al0, 16, 64); al0 += __shfl_xor(al0, 32, 64);
  al1 += __shfl_xor(al1, 16, 64); al1 += __shfl_xor(al1, 32, 64);
  al2 += __shfl_xor(al2, 16, 64); al2 += __shfl_xor(al2, 32, 64);
  al3 += __shfl_xor(al3, 16, 64); al3 += __shfl_xor(al3, 32, 64);
  ah0 += __shfl_xor(ah0, 16, 64); ah0 += __shfl_xor(ah0, 32, 64);
  ah1 += __shfl_xor(ah1, 16, 64); ah1 += __shfl_xor(ah1, 32, 64);
  ah2 += __shfl_xor(ah2, 16, 64); ah2 += __shfl_xor(ah2, 32, 64);
  ah3 += __shfl_xor(ah3, 16, 64); ah3 += __shfl_xor(ah3, 32, 64);
  float rd0 = 1.f / fmaxf(d0, 1e-9f), rd1 = 1.f / fmaxf(d1, 1e-9f);
  float ol0 = fmaxf(al0 * rd0, 0.f), ol1 = fmaxf(al1 * rd0, 0.f);
  float ol2 = fmaxf(al2 * rd0, 0.f), ol3 = fmaxf(al3 * rd0, 0.f);
  float oh0 = fmaxf(ah0 * rd1, 0.f), oh1 = fmaxf(ah1 * rd1, 0.f);
  float oh2 = fmaxf(ah2 * rd1, 0.f), oh3 = fmaxf(ah3 * rd1, 0.f);
  float s1 = ol0 + ol1 + ol2 + ol3 + oh0 + oh1 + oh2 + oh3;
  float s2 = ol0 * ol0 + ol1 * ol1 + ol2 * ol2 + ol3 * ol3 +
             oh0 * oh0 + oh1 * oh1 + oh2 * oh2 + oh3 * oh3;
  s1 = rowsum16(s1);
  s2 = rowsum16(s2);
  float mean = s1 * (1.f / 128.f);
  float var = s2 * (1.f / 128.f) - mean * mean;
  float rs = rsqrtf(var + 1e-5f);
  if (e == 0) {
    floatx4 gl = *(const floatx4*)(g + dd * 4);
    floatx4 bl = *(const floatx4*)(bb + dd * 4);
    floatx4 gh = *(const floatx4*)(g + 64 + dd * 4);
    floatx4 bh = *(const floatx4*)(bb + 64 + dd * 4);
    float hl0 = (ol0 - mean) * rs * gl[0] + bl[0];
    float hl1 = (ol1 - mean) * rs * gl[1] + bl[1];
    float hl2 = (ol2 - mean) * rs * gl[2] + bl[2];
    float hl3 = (ol3 - mean) * rs * gl[3] + bl[3];
    float hh0 = (oh0 - mean) * rs * gh[0] + bh[0];
    float hh1 = (oh1 - mean) * rs * gh[1] + bh[1];
    float hh2 = (oh2 - mean) * rs * gh[2] + bh[2];
    float hh3 = (oh3 - mean) * rs * gh[3] + bh[3];
    if (outp == nullptr) {
      uint2 w0, w1;
      w0.x = packbf(hl0, hl1); w0.y = packbf(hl2, hl3);
      w1.x = packbf(hh0, hh1); w1.y = packbf(hh2, hh3);
      *(uint2*)(hb + (size_t)n * 128 + dd * 4) = w0;
      *(uint2*)(hb + (size_t)n * 128 + 64 + dd * 4) = w1;
    } else {
      const float2* wo2 = (const float2*)wo;
      float2 wa0 = wo2[dd * 4], wa1 = wo2[dd * 4 + 1];
      float2 wa2 = wo2[dd * 4 + 2], wa3 = wo2[dd * 4 + 3];
      float2 wb0 = wo2[64 + dd * 4], wb1 = wo2[64 + dd * 4 + 1];
      float2 wb2 = wo2[64 + dd * 4 + 2], wb3 = wo2[64 + dd * 4 + 3];
      float p0 = hl0 * wa0.x + hl1 * wa1.x + hl2 * wa2.x + hl3 * wa3.x +
                 hh0 * wb0.x + hh1 * wb1.x + hh2 * wb2.x + hh3 * wb3.x;
      float p1 = hl0 * wa0.y + hl1 * wa1.y + hl2 * wa2.y + hl3 * wa3.y +
                 hh0 * wb0.y + hh1 * wb1.y + hh2 * wb2.y + hh3 * wb3.y;
      p0 = rowsum16(p0);
      p1 = rowsum16(p1);
      if (dd == 0) {
        outp[n * 2] = p0 + bo[0];
        outp[n * 2 + 1] = p1 + bo[1];
      }
    }
  }
}

// ---------------------------------------------------------------------------
extern "C" void kernel_launch(void* const* d_in, const int* in_sizes, int n_in,
                              void* d_out, int out_size, void* d_ws, size_t ws_size,
                              hipStream_t stream) {
  const float* x = (const float*)d_in[0];
  const float* neif = (const float*)d_in[1];
  const int* ei = (const int*)d_in[2];
  const float* w_in = (const float*)d_in[3];
  const float* b_in = (const float*)d_in[4];
  const float* mha_in_w = (const float*)d_in[5];
  const float* mha_in_b = (const float*)d_in[6];
  const float* mha_out_w = (const float*)d_in[7];
  const float* mha_out_b = (const float*)d_in[8];
  const float* w_nei = (const float*)d_in[9];
  const float* b_nei = (const float*)d_in[10];
  const float* wq = (const float*)d_in[11];
  const float* bq = (const float*)d_in[12];
  const float* wk = (const float*)d_in[13];
  const float* bk = (const float*)d_in[14];
  const float* wv = (const float*)d_in[15];
  const float* bv = (const float*)d_in[16];
  const float* ln_g = (const float*)d_in[17];
  const float* ln_b = (const float*)d_in[18];
  const float* w_out = (const float*)d_in[19];
  const float* b_out = (const float*)d_in[20];
  float* out = (float*)d_out;

  // workspace layout (~62 MB)
  char* wsb = (char*)d_ws;
  size_t off = 0;
  unsigned* q2 = (unsigned*)(wsb + off); off += (size_t)NN * 64 * 4;
  unsigned* k2 = (unsigned*)(wsb + off); off += (size_t)NN * 64 * 4;
  unsigned* v2 = (unsigned*)(wsb + off); off += (size_t)NN * 64 * 4;
  int* esrc = (int*)(wsb + off);         off += (size_t)2 * NN * 64 * 4;
  int* cnt = (int*)(wsb + off);          off += (size_t)2 * NN * 4;
  u16* Yb = (u16*)(wsb + off);           off += (size_t)NN * 256 * 2;
  u16* hb = (u16*)(wsb + off);           off += (size_t)NN * 128 * 2;
  u16* wt3 = (u16*)(wsb + off);          off += (size_t)768 * 128 * 2;
  u16* wtP2 = (u16*)(wsb + off);         off += (size_t)128 * 384 * 2;
  u16* wtQK = (u16*)(wsb + off);         off += (size_t)128 * 64 * 2;
  float* G = (float*)(wsb + off);        off += (size_t)256 * 128 * 4;
  float* fusedW = (float*)(wsb + off);   off += 64 * 128 * 4;
  float* fusedB = (float*)(wsb + off);   off += 128 * 4;
  float* fusedB2 = (float*)(wsb + off);  off += 128 * 4;

  hipMemsetAsync(cnt, 0, (size_t)2 * NN * sizeof(int), stream);
  k_fill2<<<8 * FILLB, 256, 0, stream>>>(ei, cnt, esrc);

  k_fuse<<<65, 128, 0, stream>>>(mha_out_w, mha_out_b, w_nei, b_nei, b_in, fusedW, fusedB);
  k_prepB<<<257, 128, 0, stream>>>(mha_in_w, fusedW, fusedB, mha_in_b, G, fusedB2);
  k_prep2<<<960, 128, 0, stream>>>(w_in, G, wq, wk, wv, mha_in_w, wtP2, wt3, wtQK);

  k_mha9<<<3750, 512, 0, stream>>>(neif, wtQK, mha_in_b, Yb);

  // layer 0: proj + qkv fused (h0 stays in LDS)
  k_projqkv3<<<938, 512, 0, stream>>>(x, Yb, wtP2, fusedB2, wt3,
                                      bq, bk, bv, q2, k2, v2);
  k_sagg7<<<NN / 4, 256, 0, stream>>>(q2, k2, v2, esrc, cnt,
                                      ln_g, ln_b, hb, w_out, b_out, nullptr);
  // layer 1
  k_qkv4c<<<938, 512, 0, stream>>>(hb, wt3 + (size_t)3 * 128 * 128,
                                   bq + 128, bk + 128, bv + 128, q2, k2, v2);
  k_sagg7<<<NN / 4, 256, 0, stream>>>(q2, k2, v2, esrc + (size_t)NN * 64,
                                      cnt + NN, ln_g + 128, ln_b + 128, hb,
                                      w_out, b_out, out);
}

// Round 18
// 280.276 us; speedup vs baseline: 1.0148x; 1.0148x over previous
//
#include <hip/hip_runtime.h>
#include <hip/hip_bf16.h>

#define NN 30000
#define EE 480000

typedef __attribute__((ext_vector_type(8))) short short8;
typedef __attribute__((ext_vector_type(4))) short short4v;
typedef __attribute__((ext_vector_type(4))) float floatx4;
typedef unsigned short u16;

__device__ __forceinline__ u16 f2bf(float f) {
  union { float f; unsigned u; } v; v.f = f;
  unsigned u = v.u;
  u += 0x7FFFu + ((u >> 16) & 1u);  // RNE
  return (u16)(u >> 16);
}
__device__ __forceinline__ float bf2f(u16 u) {
  union { unsigned u; float f; } v; v.u = ((unsigned)u) << 16;
  return v.f;
}
__device__ __forceinline__ float bflo(unsigned u) {
  union { unsigned x; float f; } v; v.x = u << 16; return v.f;
}
__device__ __forceinline__ float bfhi(unsigned u) {
  union { unsigned x; float f; } v; v.x = u & 0xFFFF0000u; return v.f;
}
__device__ __forceinline__ unsigned packbf(float a, float b) {
  return (unsigned)f2bf(a) | ((unsigned)f2bf(b) << 16);
}
__device__ __forceinline__ short8 pack8(float4 A, float4 B) {
  union { unsigned u[4]; short8 s; } r;
  r.u[0] = packbf(A.x, A.y);
  r.u[1] = packbf(A.z, A.w);
  r.u[2] = packbf(B.x, B.y);
  r.u[3] = packbf(B.z, B.w);
  return r.s;
}

// ---- DPP cross-lane adds (VALU pipe, no LDS) ----
template <int CTRL>
__device__ __forceinline__ float dppadd(float v) {
  int s = __builtin_amdgcn_update_dpp(0, __builtin_bit_cast(int, v), CTRL, 0xF, 0xF, true);
  return v + __builtin_bit_cast(float, s);
}
__device__ __forceinline__ float rowsum16(float v) {
  v = dppadd<0x121>(v); v = dppadd<0x122>(v); v = dppadd<0x124>(v); v = dppadd<0x128>(v);
  return v;
}
__device__ __forceinline__ float rowsum8(float v) {
  v = dppadd<0xB1>(v); v = dppadd<0x4E>(v); v = dppadd<0x141>(v);
  return v;
}

#define MFMA32 __builtin_amdgcn_mfma_f32_16x16x32_bf16

#if __has_builtin(__builtin_amdgcn_mfma_f32_16x16x16bf16_1k)
__device__ __forceinline__ floatx4 MFMA16(short4v a, short4v b, floatx4 c) {
  return __builtin_amdgcn_mfma_f32_16x16x16bf16_1k(a, b, c, 0, 0, 0);
}
#else
__device__ __forceinline__ floatx4 MFMA16(short4v a, short4v b, floatx4 c) {
  asm volatile("v_mfma_f32_16x16x16_bf16 %0, %1, %2, %0"
               : "+v"(c) : "v"(a), "v"(b));
  return c;
}
#endif

// ---------------------------------------------------------------------------
// k_fuse: fusedW = mha_out_w @ w_nei ; fusedB = b_in + b_nei + mha_out_b @ w_nei
// ---------------------------------------------------------------------------
__global__ __launch_bounds__(128) void k_fuse(
    const float* __restrict__ out_w, const float* __restrict__ out_b,
    const float* __restrict__ w_nei, const float* __restrict__ b_nei,
    const float* __restrict__ b_in,
    float* __restrict__ fusedW, float* __restrict__ fusedB) {
  int i = blockIdx.x, j = threadIdx.x;
  if (i < 64) {
    float a = 0.f;
    for (int kk = 0; kk < 64; ++kk) a = fmaf(out_w[i * 64 + kk], w_nei[kk * 128 + j], a);
    fusedW[i * 128 + j] = a;
  } else {
    float a = b_in[j] + b_nei[j];
    for (int kk = 0; kk < 64; ++kk) a = fmaf(out_b[kk], w_nei[kk * 128 + j], a);
    fusedB[j] = a;
  }
}

// merged: blocks 0-255 -> G rows; block 256 -> fusedB2
__global__ __launch_bounds__(128) void k_prepB(
    const float* __restrict__ in_w, const float* __restrict__ fusedW,
    const float* __restrict__ fusedB, const float* __restrict__ in_b,
    float* __restrict__ G, float* __restrict__ fusedB2) {
  int bx = blockIdx.x, c = threadIdx.x;
  if (bx < 256) {
    int h = bx >> 6, d = bx & 63;
    float a = 0.f;
    for (int dd = 0; dd < 16; ++dd)
      a = fmaf(in_w[d * 192 + 128 + h * 16 + dd], fusedW[(h * 16 + dd) * 128 + c], a);
    G[bx * 128 + c] = a;
  } else {
    float a = fusedB[c];
    for (int d = 0; d < 64; ++d) a = fmaf(in_b[128 + d], fusedW[d * 128 + c], a);
    fusedB2[c] = a;
  }
}

// merged: blocks 0-127 -> wtP2; 128-895 -> wt3; 896-959 -> wtQK
__global__ __launch_bounds__(128) void k_prep2(
    const float* __restrict__ w_in, const float* __restrict__ G,
    const float* __restrict__ wq, const float* __restrict__ wk,
    const float* __restrict__ wv, const float* __restrict__ in_w,
    u16* __restrict__ wtP2, u16* __restrict__ wt3, u16* __restrict__ wtQK) {
  int bx = blockIdx.x, t = threadIdx.x;
  if (bx < 128) {
    int c = bx;
#pragma unroll
    for (int part = 0; part < 3; ++part) {
      int k = part * 128 + t;
      float v = (k < 128) ? w_in[(size_t)k * 128 + c] : G[(size_t)(k - 128) * 128 + c];
      wtP2[(size_t)c * 384 + k] = f2bf(v);
    }
  } else if (bx < 896) {
    int b2 = bx - 128;
    int l = b2 / 384, rem = b2 % 384, o = rem >> 7, c = rem & 127;
    const float* w = (o == 0 ? wq : (o == 1 ? wk : wv)) + (size_t)l * 16384;
    wt3[(size_t)b2 * 128 + t] = f2bf(w[(size_t)t * 128 + c]);
  } else {
    int c = (bx - 896) * 2 + (t >> 6), kk = t & 63;
    float s = (c < 64) ? 0.25f : 1.f;
    wtQK[(size_t)c * 64 + kk] = f2bf(s * in_w[(size_t)kk * 192 + c]);
  }
}

// ---------------------------------------------------------------------------
// k_mha9: fused QK-GEMM + per-node attention colsums + Y (round-13 version).
// ---------------------------------------------------------------------------
__global__ __launch_bounds__(512) void k_mha9(
    const float* __restrict__ xn,    // nei_features [300000,64] f32
    const u16* __restrict__ wtQK,    // [128][64] bf16
    const float* __restrict__ in_b,  // [192]
    u16* __restrict__ Yb) {          // [NN,256]
  __shared__ unsigned qks[80 * 66];
  __shared__ float cs_lds[8][4][12];
  int t = threadIdx.x, w = t >> 6, l = t & 63;
  int lr = l & 15, lq = l >> 4;
  const floatx4 zf = {0.f, 0.f, 0.f, 0.f};
  size_t r0 = (size_t)blockIdx.x * 80;

  if (w < 5) {
    int row = w * 16 + lr;
    size_t arow = r0 + row;
    const float* xp = xn + arow * 64 + lq * 8;
    float4 f0 = *(const float4*)xp;
    float4 f1 = *(const float4*)(xp + 4);
    float4 f2 = *(const float4*)(xp + 32);
    float4 f3 = *(const float4*)(xp + 36);
    short8 a0 = pack8(f0, f1), a1 = pack8(f2, f3);
    floatx4 acc[8];
#pragma unroll
    for (int ct = 0; ct < 8; ++ct) acc[ct] = zf;
#pragma unroll
    for (int ct = 0; ct < 8; ++ct) {
      const short8* bp = (const short8*)(wtQK + (size_t)(ct * 16 + lr) * 64);
      acc[ct] = MFMA32(a0, bp[lq], acc[ct], 0, 0, 0);
      acc[ct] = MFMA32(a1, bp[4 + lq], acc[ct], 0, 0, 0);
    }
#pragma unroll
    for (int ct = 0; ct < 4; ++ct) {
      float bq_ = in_b[ct * 16 + lr] * 0.25f;
      float bk_ = in_b[64 + ct * 16 + lr];
#pragma unroll
      for (int r = 0; r < 4; ++r)
        qks[(w * 16 + lq * 4 + r) * 66 + ct * 16 + lr] =
            packbf(acc[ct][r] + bq_, acc[ct + 4][r] + bk_);
    }
  }
  __syncthreads();

  int seqc = lr < 10 ? lr : 9;
  {
#pragma unroll
    for (int h = 0; h < 4; ++h) {
      const unsigned* rp = &qks[(w * 10 + seqc) * 66 + h * 16 + lq * 4];
      uint2 u0 = *(const uint2*)rp;
      uint2 u1 = *(const uint2*)(rp + 2);
      union { unsigned u[2]; short4v s; } qv, kv;
      qv.u[0] = (u0.x & 0xFFFFu) | (u0.y << 16);
      qv.u[1] = (u1.x & 0xFFFFu) | (u1.y << 16);
      kv.u[0] = (u0.x >> 16) | (u0.y & 0xFFFF0000u);
      kv.u[1] = (u1.x >> 16) | (u1.y & 0xFFFF0000u);
      floatx4 s4 = MFMA16(kv.s, qv.s, zf);   // S^T[j=lq*4+r][i=lr]
      int j0 = lq * 4;
      float e0 = (j0 + 0 < 10) ? __expf(s4[0]) : 0.f;
      float e1 = (j0 + 1 < 10) ? __expf(s4[1]) : 0.f;
      float e2 = (j0 + 2 < 10) ? __expf(s4[2]) : 0.f;
      float e3 = (j0 + 3 < 10) ? __expf(s4[3]) : 0.f;
      float den = e0 + e1 + e2 + e3;
      den += __shfl_xor(den, 16, 64);
      den += __shfl_xor(den, 32, 64);
      float rden = 0.1f / den;  // fold seq-mean 1/10
      float v0 = (lr < 10) ? e0 * rden : 0.f;
      float v1 = (lr < 10) ? e1 * rden : 0.f;
      float v2 = (lr < 10) ? e2 * rden : 0.f;
      float v3 = (lr < 10) ? e3 * rden : 0.f;
      v0 = rowsum16(v0);
      v1 = rowsum16(v1);
      v2 = rowsum16(v2);
      v3 = rowsum16(v3);
      if (lr == 0) {
        cs_lds[w][h][lq * 4 + 0] = v0;
        cs_lds[w][h][lq * 4 + 1] = v1;
        cs_lds[w][h][lq * 4 + 2] = v2;
        cs_lds[w][h][lq * 4 + 3] = v3;
      }
    }
    size_t node = (size_t)blockIdx.x * 8 + w;
    const float* xp2 = xn + node * 640 + l;  // lane l = dim d
    float y0 = 0.f, y1 = 0.f, y2 = 0.f, y3 = 0.f;
#pragma unroll
    for (int j = 0; j < 10; ++j) {
      float xv = xp2[j * 64];                // coalesced 256B, cache-warm
      y0 = fmaf(cs_lds[w][0][j], xv, y0);
      y1 = fmaf(cs_lds[w][1][j], xv, y1);
      y2 = fmaf(cs_lds[w][2][j], xv, y2);
      y3 = fmaf(cs_lds[w][3][j], xv, y3);
    }
    size_t yb = node * 256;
    Yb[yb + l] = f2bf(y0);
    Yb[yb + 64 + l] = f2bf(y1);
    Yb[yb + 128 + l] = f2bf(y2);
    Yb[yb + 192 + l] = f2bf(y3);
  }
}

// ---------------------------------------------------------------------------
// k_projqkv4: round-16 tiling (64 rows/block, 512 thr) + explicit B-fragment
// prefetch arrays so each MFMA chain pays ONE load latency, not twelve.
// ---------------------------------------------------------------------------
__global__ __launch_bounds__(512) void k_projqkv4(
    const float* __restrict__ x, const u16* __restrict__ Yb,
    const u16* __restrict__ wtP2, const float* __restrict__ fusedB2,
    const u16* __restrict__ wt3l,
    const float* __restrict__ bqL, const float* __restrict__ bkL,
    const float* __restrict__ bvL,
    unsigned* __restrict__ q2, unsigned* __restrict__ k2, unsigned* __restrict__ v2) {
  __shared__ u16 hs[64 * 128];
  int t = threadIdx.x, w = t >> 6, l = t & 63, lr = l & 15, lq = l >> 4;
  int wr = w & 3, half = w >> 2;
  int row0 = blockIdx.x * 64 + wr * 16;
  int arow = row0 + lr; if (arow >= NN) arow = NN - 1;
  // ---- phase A: h0 tile (rows wr*16, cols half*64) ----
  {
    const float* xp = x + (size_t)arow * 128;
    const short8* yp = (const short8*)(Yb + (size_t)arow * 256);
    short8 afr[12];
#pragma unroll
    for (int kb = 0; kb < 4; ++kb) {
      float4 fa = *(const float4*)(xp + kb * 32 + lq * 8);
      float4 fb = *(const float4*)(xp + kb * 32 + lq * 8 + 4);
      afr[kb] = pack8(fa, fb);
    }
#pragma unroll
    for (int m = 0; m < 8; ++m) afr[4 + m] = yp[m * 4 + lq];
    floatx4 acc[4];
#pragma unroll
    for (int ct = 0; ct < 4; ++ct) acc[ct] = (floatx4){0.f, 0.f, 0.f, 0.f};
#pragma unroll
    for (int ct = 0; ct < 4; ++ct) {
      int ctg = half * 4 + ct;
      const short8* bp = (const short8*)(wtP2 + (size_t)(ctg * 16 + lr) * 384);
      short8 bfr[12];
#pragma unroll
      for (int kb = 0; kb < 12; ++kb) bfr[kb] = bp[kb * 4 + lq];   // batch loads
#pragma unroll
      for (int kb = 0; kb < 12; ++kb)
        acc[ct] = MFMA32(afr[kb], bfr[kb], acc[ct], 0, 0, 0);      // pure MFMA chain
    }
#pragma unroll
    for (int ct = 0; ct < 4; ++ct) {
      int ctg = half * 4 + ct;
      int col = ctg * 16 + lr;
      float bias = fusedB2[col];
#pragma unroll
      for (int r = 0; r < 4; ++r)
        hs[(wr * 16 + lq * 4 + r) * 128 + col] = f2bf(acc[ct][r] + bias);
    }
  }
  __syncthreads();
  // ---- phase B: layer-0 QKV; 6 col-pairs, B-frags batch-prefetched ----
  {
    int lrow = wr * 16 + lr;
    const short8* ap = (const short8*)(hs + lrow * 128);
    short8 a0 = ap[lq], a1 = ap[4 + lq], a2 = ap[8 + lq], a3 = ap[12 + lq];
    const short8* wt8 = (const short8*)wt3l;
    floatx4 accL[6], accH[6];
#pragma unroll
    for (int p = 0; p < 6; ++p) {
      accL[p] = (floatx4){0.f, 0.f, 0.f, 0.f};
      accH[p] = (floatx4){0.f, 0.f, 0.f, 0.f};
    }
#pragma unroll
    for (int p = 0; p < 6; ++p) {
      int pg = half * 6 + p;
      int o = pg >> 2, cc = pg & 3;
      const short8* bpL = wt8 + (size_t)(o * 128 + cc * 16 + lr) * 16;
      const short8* bpH = wt8 + (size_t)(o * 128 + (cc + 4) * 16 + lr) * 16;
      short8 bl[4], bh[4];
#pragma unroll
      for (int kb = 0; kb < 4; ++kb) { bl[kb] = bpL[kb * 4 + lq]; bh[kb] = bpH[kb * 4 + lq]; }
      accL[p] = MFMA32(a0, bl[0], accL[p], 0, 0, 0);
      accL[p] = MFMA32(a1, bl[1], accL[p], 0, 0, 0);
      accL[p] = MFMA32(a2, bl[2], accL[p], 0, 0, 0);
      accL[p] = MFMA32(a3, bl[3], accL[p], 0, 0, 0);
      accH[p] = MFMA32(a0, bh[0], accH[p], 0, 0, 0);
      accH[p] = MFMA32(a1, bh[1], accH[p], 0, 0, 0);
      accH[p] = MFMA32(a2, bh[2], accH[p], 0, 0, 0);
      accH[p] = MFMA32(a3, bh[3], accH[p], 0, 0, 0);
    }
#pragma unroll
    for (int p = 0; p < 6; ++p) {
      int pg = half * 6 + p;
      int o = pg >> 2, cc = pg & 3;
      unsigned* op = o == 0 ? q2 : (o == 1 ? k2 : v2);
      const float* bp2 = o == 0 ? bqL : (o == 1 ? bkL : bvL);
      int col = cc * 16 + lr;
      float blo = bp2[col], bhi = bp2[64 + col];
#pragma unroll
      for (int r = 0; r < 4; ++r) {
        int row = row0 + lq * 4 + r;
        if (row < NN)
          op[(size_t)row * 64 + col] = packbf(accL[p][r] + blo, accH[p][r] + bhi);
      }
    }
  }
}

// ---------------------------------------------------------------------------
// k_qkv4d: round-16 tiling + explicit B-fragment prefetch (as above).
// ---------------------------------------------------------------------------
__global__ __launch_bounds__(512) void k_qkv4d(
    const u16* __restrict__ hb, const u16* __restrict__ wt3l,
    const float* __restrict__ bqL, const float* __restrict__ bkL,
    const float* __restrict__ bvL,
    unsigned* __restrict__ q2, unsigned* __restrict__ k2, unsigned* __restrict__ v2) {
  int t = threadIdx.x, w = t >> 6, l = t & 63, lr = l & 15, lq = l >> 4;
  int wr = w & 3, half = w >> 2;
  int row0 = blockIdx.x * 64 + wr * 16;
  int arow = row0 + lr; if (arow >= NN) arow = NN - 1;
  const short8* ap = (const short8*)(hb + (size_t)arow * 128);
  short8 a0 = ap[lq], a1 = ap[4 + lq], a2 = ap[8 + lq], a3 = ap[12 + lq];
  const short8* wt8 = (const short8*)wt3l;
  floatx4 accL[6], accH[6];
#pragma unroll
  for (int p = 0; p < 6; ++p) {
    accL[p] = (floatx4){0.f, 0.f, 0.f, 0.f};
    accH[p] = (floatx4){0.f, 0.f, 0.f, 0.f};
  }
#pragma unroll
  for (int p = 0; p < 6; ++p) {
    int pg = half * 6 + p;
    int o = pg >> 2, cc = pg & 3;
    const short8* bpL = wt8 + (size_t)(o * 128 + cc * 16 + lr) * 16;
    const short8* bpH = wt8 + (size_t)(o * 128 + (cc + 4) * 16 + lr) * 16;
    short8 bl[4], bh[4];
#pragma unroll
    for (int kb = 0; kb < 4; ++kb) { bl[kb] = bpL[kb * 4 + lq]; bh[kb] = bpH[kb * 4 + lq]; }
    accL[p] = MFMA32(a0, bl[0], accL[p], 0, 0, 0);
    accL[p] = MFMA32(a1, bl[1], accL[p], 0, 0, 0);
    accL[p] = MFMA32(a2, bl[2], accL[p], 0, 0, 0);
    accL[p] = MFMA32(a3, bl[3], accL[p], 0, 0, 0);
    accH[p] = MFMA32(a0, bh[0], accH[p], 0, 0, 0);
    accH[p] = MFMA32(a1, bh[1], accH[p], 0, 0, 0);
    accH[p] = MFMA32(a2, bh[2], accH[p], 0, 0, 0);
    accH[p] = MFMA32(a3, bh[3], accH[p], 0, 0, 0);
  }
#pragma unroll
  for (int p = 0; p < 6; ++p) {
    int pg = half * 6 + p;
    int o = pg >> 2, cc = pg & 3;
    unsigned* op = o == 0 ? q2 : (o == 1 ? k2 : v2);
    const float* bp2 = o == 0 ? bqL : (o == 1 ? bkL : bvL);
    int col = cc * 16 + lr;
    float blo = bp2[col], bhi = bp2[64 + col];
#pragma unroll
    for (int r = 0; r < 4; ++r) {
      int row = row0 + lq * 4 + r;
      if (row < NN)
        op[(size_t)row * 64 + col] = packbf(accL[p][r] + blo, accH[p][r] + bhi);
    }
  }
}

// ---------------------------------------------------------------------------
// k_fill2: XCD-sliced bucketed adjacency.
// ---------------------------------------------------------------------------
#define FILLB 469
__global__ __launch_bounds__(256) void k_fill2(const int* __restrict__ ei,
                                               int* __restrict__ cnt,
                                               int* __restrict__ esrc) {
  int bx = blockIdx.x;
  int grp = bx & 7, bi = bx >> 3;
  int lo = grp * (NN / 8), hi = lo + (NN / 8);
  int tid = bi * 256 + threadIdx.x;
#pragma unroll
  for (int it = 0; it < 8; ++it) {
    int e = tid + it * (FILLB * 256);
    if (e < 2 * EE) {
      int l = e >= EE;
      int ee = e - l * EE;
      int d = ei[(size_t)(2 * l + 1) * EE + ee];
      if (d >= lo && d < hi) {
        int s = ei[(size_t)(2 * l) * EE + ee];
        int c = atomicAdd(&cnt[l * NN + d], 1);
        if (c < 64) esrc[((size_t)l * NN + d) * 64 + c] = s;
      }
    }
  }
}

// ---------------------------------------------------------------------------
// k_sagg7: fused edge-score + segment-softmax (no max) + PV + ReLU + LN.
// ---------------------------------------------------------------------------
__global__ __launch_bounds__(256) void k_sagg7(
    const unsigned* __restrict__ q2, const unsigned* __restrict__ k2,
    const unsigned* __restrict__ v2, const int* __restrict__ esrc,
    const int* __restrict__ cnt, const float* __restrict__ g,
    const float* __restrict__ bb, u16* __restrict__ hb,
    const float* __restrict__ wo, const float* __restrict__ bo,
    float* __restrict__ outp) {
  const float SC = 0.17677669529663687f;
  int t = threadIdx.x, w = t >> 6, l = t & 63;
  int e = l >> 4, dd = l & 15;
  int n = blockIdx.x * 4 + w;
  int deg = cnt[n]; if (deg > 64) deg = 64;
  const int* sp = esrc + (size_t)n * 64;
  uint4 qp = *(const uint4*)(q2 + (size_t)n * 64 + dd * 4);
  float ql0 = bflo(qp.x), ql1 = bflo(qp.y), ql2 = bflo(qp.z), ql3 = bflo(qp.w);
  float qh0 = bfhi(qp.x), qh1 = bfhi(qp.y), qh2 = bfhi(qp.z), qh3 = bfhi(qp.w);
  float dA0 = 0.f, dA1 = 0.f, dB0 = 0.f, dB1 = 0.f;
  float alA0 = 0.f, alA1 = 0.f, alA2 = 0.f, alA3 = 0.f;
  float ahA0 = 0.f, ahA1 = 0.f, ahA2 = 0.f, ahA3 = 0.f;
  float alB0 = 0.f, alB1 = 0.f, alB2 = 0.f, alB3 = 0.f;
  float ahB0 = 0.f, ahB1 = 0.f, ahB2 = 0.f, ahB3 = 0.f;
  uint4 kA = {0, 0, 0, 0}, vA = {0, 0, 0, 0};
  uint4 kB = {0, 0, 0, 0}, vB = {0, 0, 0, 0};
  bool mA = false, mB = false;
  if (deg > 0) {
    int iA = e < deg ? e : deg - 1;           mA = e < deg;
    int iB = 4 + e < deg ? 4 + e : deg - 1;   mB = 4 + e < deg;
    int sA = sp[iA], sB = sp[iB];
    kA = *(const uint4*)(k2 + (size_t)sA * 64 + dd * 4);
    vA = *(const uint4*)(v2 + (size_t)sA * 64 + dd * 4);
    kB = *(const uint4*)(k2 + (size_t)sB * 64 + dd * 4);
    vB = *(const uint4*)(v2 + (size_t)sB * 64 + dd * 4);
  }
  for (int base = 0; base < deg; base += 8) {
    uint4 kAn = {0, 0, 0, 0}, vAn = {0, 0, 0, 0};
    uint4 kBn = {0, 0, 0, 0}, vBn = {0, 0, 0, 0};
    bool mAn = false, mBn = false;
    int nb = base + 8;
    if (nb < deg) {
      int iA = nb + e < deg ? nb + e : deg - 1;         mAn = nb + e < deg;
      int iB = nb + 4 + e < deg ? nb + 4 + e : deg - 1; mBn = nb + 4 + e < deg;
      int sA = sp[iA], sB = sp[iB];
      kAn = *(const uint4*)(k2 + (size_t)sA * 64 + dd * 4);
      vAn = *(const uint4*)(v2 + (size_t)sA * 64 + dd * 4);
      kBn = *(const uint4*)(k2 + (size_t)sB * 64 + dd * 4);
      vBn = *(const uint4*)(v2 + (size_t)sB * 64 + dd * 4);
    }
    float rA0 = ql0 * bflo(kA.x) + ql1 * bflo(kA.y) + ql2 * bflo(kA.z) + ql3 * bflo(kA.w);
    float rA1 = qh0 * bfhi(kA.x) + qh1 * bfhi(kA.y) + qh2 * bfhi(kA.z) + qh3 * bfhi(kA.w);
    float rB0 = ql0 * bflo(kB.x) + ql1 * bflo(kB.y) + ql2 * bflo(kB.z) + ql3 * bflo(kB.w);
    float rB1 = qh0 * bfhi(kB.x) + qh1 * bfhi(kB.y) + qh2 * bfhi(kB.z) + qh3 * bfhi(kB.w);
    rA0 = rowsum8(rA0); rA1 = rowsum8(rA1);
    rB0 = rowsum8(rB0); rB1 = rowsum8(rB1);
    float pA0 = mA ? __expf(rA0 * SC) : 0.f;
    float pA1 = mA ? __expf(rA1 * SC) : 0.f;
    float pB0 = mB ? __expf(rB0 * SC) : 0.f;
    float pB1 = mB ? __expf(rB1 * SC) : 0.f;
    dA0 += pA0; dA1 += pA1; dB0 += pB0; dB1 += pB1;
    alA0 = fmaf(pA0, bflo(vA.x), alA0); alA1 = fmaf(pA0, bflo(vA.y), alA1);
    alA2 = fmaf(pA0, bflo(vA.z), alA2); alA3 = fmaf(pA0, bflo(vA.w), alA3);
    ahA0 = fmaf(pA1, bfhi(vA.x), ahA0); ahA1 = fmaf(pA1, bfhi(vA.y), ahA1);
    ahA2 = fmaf(pA1, bfhi(vA.z), ahA2); ahA3 = fmaf(pA1, bfhi(vA.w), ahA3);
    alB0 = fmaf(pB0, bflo(vB.x), alB0); alB1 = fmaf(pB0, bflo(vB.y), alB1);
    alB2 = fmaf(pB0, bflo(vB.z), alB2); alB3 = fmaf(pB0, bflo(vB.w), alB3);
    ahB0 = fmaf(pB1, bfhi(vB.x), ahB0); ahB1 = fmaf(pB1, bfhi(vB.y), ahB1);
    ahB2 = fmaf(pB1, bfhi(vB.z), ahB2); ahB3 = fmaf(pB1, bfhi(vB.w), ahB3);
    kA = kAn; vA = vAn; mA = mAn;
    kB = kBn; vB = vBn; mB = mBn;
  }
  float d0 = dA0 + dB0, d1 = dA1 + dB1;
  float al0 = alA0 + alB0, al1 = alA1 + alB1, al2 = alA2 + alB2, al3 = alA3 + alB3;
  float ah0 = ahA0 + ahB0, ah1 = ahA1 + ahB1, ah2 = ahA2 + ahB2, ah3 = ahA3 + ahB3;
  d0 += __shfl_xor(d0, 16, 64); d0 += __shfl_xor(d0, 32, 64);
  d1 += __shfl_xor(d1, 16, 64); d1 += __shfl_xor(d1, 32, 64);
  al0 += __shfl_xor(al0, 16, 64); al0 += __shfl_xor(al0, 32, 64);
  al1 += __shfl_xor(al1, 16, 64); al1 += __shfl_xor(al1, 32, 64);
  al2 += __shfl_xor(al2, 16, 64); al2 += __shfl_xor(al2, 32, 64);
  al3 += __shfl_xor(al3, 16, 64); al3 += __shfl_xor(al3, 32, 64);
  ah0 += __shfl_xor(ah0, 16, 64); ah0 += __shfl_xor(ah0, 32, 64);
  ah1 += __shfl_xor(ah1, 16, 64); ah1 += __shfl_xor(ah1, 32, 64);
  ah2 += __shfl_xor(ah2, 16, 64); ah2 += __shfl_xor(ah2, 32, 64);
  ah3 += __shfl_xor(ah3, 16, 64); ah3 += __shfl_xor(ah3, 32, 64);
  float rd0 = 1.f / fmaxf(d0, 1e-9f), rd1 = 1.f / fmaxf(d1, 1e-9f);
  float ol0 = fmaxf(al0 * rd0, 0.f), ol1 = fmaxf(al1 * rd0, 0.f);
  float ol2 = fmaxf(al2 * rd0, 0.f), ol3 = fmaxf(al3 * rd0, 0.f);
  float oh0 = fmaxf(ah0 * rd1, 0.f), oh1 = fmaxf(ah1 * rd1, 0.f);
  float oh2 = fmaxf(ah2 * rd1, 0.f), oh3 = fmaxf(ah3 * rd1, 0.f);
  float s1 = ol0 + ol1 + ol2 + ol3 + oh0 + oh1 + oh2 + oh3;
  float s2 = ol0 * ol0 + ol1 * ol1 + ol2 * ol2 + ol3 * ol3 +
             oh0 * oh0 + oh1 * oh1 + oh2 * oh2 + oh3 * oh3;
  s1 = rowsum16(s1);
  s2 = rowsum16(s2);
  float mean = s1 * (1.f / 128.f);
  float var = s2 * (1.f / 128.f) - mean * mean;
  float rs = rsqrtf(var + 1e-5f);
  if (e == 0) {
    floatx4 gl = *(const floatx4*)(g + dd * 4);
    floatx4 bl = *(const floatx4*)(bb + dd * 4);
    floatx4 gh = *(const floatx4*)(g + 64 + dd * 4);
    floatx4 bh = *(const floatx4*)(bb + 64 + dd * 4);
    float hl0 = (ol0 - mean) * rs * gl[0] + bl[0];
    float hl1 = (ol1 - mean) * rs * gl[1] + bl[1];
    float hl2 = (ol2 - mean) * rs * gl[2] + bl[2];
    float hl3 = (ol3 - mean) * rs * gl[3] + bl[3];
    float hh0 = (oh0 - mean) * rs * gh[0] + bh[0];
    float hh1 = (oh1 - mean) * rs * gh[1] + bh[1];
    float hh2 = (oh2 - mean) * rs * gh[2] + bh[2];
    float hh3 = (oh3 - mean) * rs * gh[3] + bh[3];
    if (outp == nullptr) {
      uint2 w0, w1;
      w0.x = packbf(hl0, hl1); w0.y = packbf(hl2, hl3);
      w1.x = packbf(hh0, hh1); w1.y = packbf(hh2, hh3);
      *(uint2*)(hb + (size_t)n * 128 + dd * 4) = w0;
      *(uint2*)(hb + (size_t)n * 128 + 64 + dd * 4) = w1;
    } else {
      const float2* wo2 = (const float2*)wo;
      float2 wa0 = wo2[dd * 4], wa1 = wo2[dd * 4 + 1];
      float2 wa2 = wo2[dd * 4 + 2], wa3 = wo2[dd * 4 + 3];
      float2 wb0 = wo2[64 + dd * 4], wb1 = wo2[64 + dd * 4 + 1];
      float2 wb2 = wo2[64 + dd * 4 + 2], wb3 = wo2[64 + dd * 4 + 3];
      float p0 = hl0 * wa0.x + hl1 * wa1.x + hl2 * wa2.x + hl3 * wa3.x +
                 hh0 * wb0.x + hh1 * wb1.x + hh2 * wb2.x + hh3 * wb3.x;
      float p1 = hl0 * wa0.y + hl1 * wa1.y + hl2 * wa2.y + hl3 * wa3.y +
                 hh0 * wb0.y + hh1 * wb1.y + hh2 * wb2.y + hh3 * wb3.y;
      p0 = rowsum16(p0);
      p1 = rowsum16(p1);
      if (dd == 0) {
        outp[n * 2] = p0 + bo[0];
        outp[n * 2 + 1] = p1 + bo[1];
      }
    }
  }
}

// ---------------------------------------------------------------------------
extern "C" void kernel_launch(void* const* d_in, const int* in_sizes, int n_in,
                              void* d_out, int out_size, void* d_ws, size_t ws_size,
                              hipStream_t stream) {
  const float* x = (const float*)d_in[0];
  const float* neif = (const float*)d_in[1];
  const int* ei = (const int*)d_in[2];
  const float* w_in = (const float*)d_in[3];
  const float* b_in = (const float*)d_in[4];
  const float* mha_in_w = (const float*)d_in[5];
  const float* mha_in_b = (const float*)d_in[6];
  const float* mha_out_w = (const float*)d_in[7];
  const float* mha_out_b = (const float*)d_in[8];
  const float* w_nei = (const float*)d_in[9];
  const float* b_nei = (const float*)d_in[10];
  const float* wq = (const float*)d_in[11];
  const float* bq = (const float*)d_in[12];
  const float* wk = (const float*)d_in[13];
  const float* bk = (const float*)d_in[14];
  const float* wv = (const float*)d_in[15];
  const float* bv = (const float*)d_in[16];
  const float* ln_g = (const float*)d_in[17];
  const float* ln_b = (const float*)d_in[18];
  const float* w_out = (const float*)d_in[19];
  const float* b_out = (const float*)d_in[20];
  float* out = (float*)d_out;

  // workspace layout (~62 MB)
  char* wsb = (char*)d_ws;
  size_t off = 0;
  unsigned* q2 = (unsigned*)(wsb + off); off += (size_t)NN * 64 * 4;
  unsigned* k2 = (unsigned*)(wsb + off); off += (size_t)NN * 64 * 4;
  unsigned* v2 = (unsigned*)(wsb + off); off += (size_t)NN * 64 * 4;
  int* esrc = (int*)(wsb + off);         off += (size_t)2 * NN * 64 * 4;
  int* cnt = (int*)(wsb + off);          off += (size_t)2 * NN * 4;
  u16* Yb = (u16*)(wsb + off);           off += (size_t)NN * 256 * 2;
  u16* hb = (u16*)(wsb + off);           off += (size_t)NN * 128 * 2;
  u16* wt3 = (u16*)(wsb + off);          off += (size_t)768 * 128 * 2;
  u16* wtP2 = (u16*)(wsb + off);         off += (size_t)128 * 384 * 2;
  u16* wtQK = (u16*)(wsb + off);         off += (size_t)128 * 64 * 2;
  float* G = (float*)(wsb + off);        off += (size_t)256 * 128 * 4;
  float* fusedW = (float*)(wsb + off);   off += 64 * 128 * 4;
  float* fusedB = (float*)(wsb + off);   off += 128 * 4;
  float* fusedB2 = (float*)(wsb + off);  off += 128 * 4;

  hipMemsetAsync(cnt, 0, (size_t)2 * NN * sizeof(int), stream);
  k_fill2<<<8 * FILLB, 256, 0, stream>>>(ei, cnt, esrc);

  k_fuse<<<65, 128, 0, stream>>>(mha_out_w, mha_out_b, w_nei, b_nei, b_in, fusedW, fusedB);
  k_prepB<<<257, 128, 0, stream>>>(mha_in_w, fusedW, fusedB, mha_in_b, G, fusedB2);
  k_prep2<<<960, 128, 0, stream>>>(w_in, G, wq, wk, wv, mha_in_w, wtP2, wt3, wtQK);

  k_mha9<<<3750, 512, 0, stream>>>(neif, wtQK, mha_in_b, Yb);

  // layer 0: proj + qkv fused (h0 stays in LDS)
  k_projqkv4<<<469, 512, 0, stream>>>(x, Yb, wtP2, fusedB2, wt3,
                                      bq, bk, bv, q2, k2, v2);
  k_sagg7<<<NN / 4, 256, 0, stream>>>(q2, k2, v2, esrc, cnt,
                                      ln_g, ln_b, hb, w_out, b_out, nullptr);
  // layer 1
  k_qkv4d<<<469, 512, 0, stream>>>(hb, wt3 + (size_t)3 * 128 * 128,
                                   bq + 128, bk + 128, bv + 128, q2, k2, v2);
  k_sagg7<<<NN / 4, 256, 0, stream>>>(q2, k2, v2, esrc + (size_t)NN * 64,
                                      cnt + NN, ln_g + 128, ln_b + 128, hb,
                                      w_out, b_out, out);
}

// Round 19
// 270.353 us; speedup vs baseline: 1.0521x; 1.0367x over previous
//
#include <hip/hip_runtime.h>
#include <hip/hip_bf16.h>

#define NN 30000
#define EE 480000

typedef __attribute__((ext_vector_type(8))) short short8;
typedef __attribute__((ext_vector_type(4))) short short4v;
typedef __attribute__((ext_vector_type(4))) float floatx4;
typedef unsigned short u16;

__device__ __forceinline__ u16 f2bf(float f) {
  union { float f; unsigned u; } v; v.f = f;
  unsigned u = v.u;
  u += 0x7FFFu + ((u >> 16) & 1u);  // RNE
  return (u16)(u >> 16);
}
__device__ __forceinline__ float bf2f(u16 u) {
  union { unsigned u; float f; } v; v.u = ((unsigned)u) << 16;
  return v.f;
}
__device__ __forceinline__ float bflo(unsigned u) {
  union { unsigned x; float f; } v; v.x = u << 16; return v.f;
}
__device__ __forceinline__ float bfhi(unsigned u) {
  union { unsigned x; float f; } v; v.x = u & 0xFFFF0000u; return v.f;
}
__device__ __forceinline__ unsigned packbf(float a, float b) {
  return (unsigned)f2bf(a) | ((unsigned)f2bf(b) << 16);
}
__device__ __forceinline__ short8 pack8(float4 A, float4 B) {
  union { unsigned u[4]; short8 s; } r;
  r.u[0] = packbf(A.x, A.y);
  r.u[1] = packbf(A.z, A.w);
  r.u[2] = packbf(B.x, B.y);
  r.u[3] = packbf(B.z, B.w);
  return r.s;
}

// ---- DPP cross-lane adds (VALU pipe, no LDS) ----
template <int CTRL>
__device__ __forceinline__ float dppadd(float v) {
  int s = __builtin_amdgcn_update_dpp(0, __builtin_bit_cast(int, v), CTRL, 0xF, 0xF, true);
  return v + __builtin_bit_cast(float, s);
}
__device__ __forceinline__ float rowsum16(float v) {
  v = dppadd<0x121>(v); v = dppadd<0x122>(v); v = dppadd<0x124>(v); v = dppadd<0x128>(v);
  return v;
}
__device__ __forceinline__ float rowsum8(float v) {
  v = dppadd<0xB1>(v); v = dppadd<0x4E>(v); v = dppadd<0x141>(v);
  return v;
}

#define MFMA32 __builtin_amdgcn_mfma_f32_16x16x32_bf16

#if __has_builtin(__builtin_amdgcn_mfma_f32_16x16x16bf16_1k)
__device__ __forceinline__ floatx4 MFMA16(short4v a, short4v b, floatx4 c) {
  return __builtin_amdgcn_mfma_f32_16x16x16bf16_1k(a, b, c, 0, 0, 0);
}
#else
__device__ __forceinline__ floatx4 MFMA16(short4v a, short4v b, floatx4 c) {
  asm volatile("v_mfma_f32_16x16x16_bf16 %0, %1, %2, %0"
               : "+v"(c) : "v"(a), "v"(b));
  return c;
}
#endif

// ---------------------------------------------------------------------------
// k_fuse: fusedW = mha_out_w @ w_nei ; fusedB = b_in + b_nei + mha_out_b @ w_nei
// ---------------------------------------------------------------------------
__global__ __launch_bounds__(128) void k_fuse(
    const float* __restrict__ out_w, const float* __restrict__ out_b,
    const float* __restrict__ w_nei, const float* __restrict__ b_nei,
    const float* __restrict__ b_in,
    float* __restrict__ fusedW, float* __restrict__ fusedB) {
  int i = blockIdx.x, j = threadIdx.x;
  if (i < 64) {
    float a = 0.f;
    for (int kk = 0; kk < 64; ++kk) a = fmaf(out_w[i * 64 + kk], w_nei[kk * 128 + j], a);
    fusedW[i * 128 + j] = a;
  } else {
    float a = b_in[j] + b_nei[j];
    for (int kk = 0; kk < 64; ++kk) a = fmaf(out_b[kk], w_nei[kk * 128 + j], a);
    fusedB[j] = a;
  }
}

// merged: blocks 0-255 -> G rows; block 256 -> fusedB2
__global__ __launch_bounds__(128) void k_prepB(
    const float* __restrict__ in_w, const float* __restrict__ fusedW,
    const float* __restrict__ fusedB, const float* __restrict__ in_b,
    float* __restrict__ G, float* __restrict__ fusedB2) {
  int bx = blockIdx.x, c = threadIdx.x;
  if (bx < 256) {
    int h = bx >> 6, d = bx & 63;
    float a = 0.f;
    for (int dd = 0; dd < 16; ++dd)
      a = fmaf(in_w[d * 192 + 128 + h * 16 + dd], fusedW[(h * 16 + dd) * 128 + c], a);
    G[bx * 128 + c] = a;
  } else {
    float a = fusedB[c];
    for (int d = 0; d < 64; ++d) a = fmaf(in_b[128 + d], fusedW[d * 128 + c], a);
    fusedB2[c] = a;
  }
}

// merged: blocks 0-127 -> wtP2; 128-895 -> wt3; 896-959 -> wtQK
__global__ __launch_bounds__(128) void k_prep2(
    const float* __restrict__ w_in, const float* __restrict__ G,
    const float* __restrict__ wq, const float* __restrict__ wk,
    const float* __restrict__ wv, const float* __restrict__ in_w,
    u16* __restrict__ wtP2, u16* __restrict__ wt3, u16* __restrict__ wtQK) {
  int bx = blockIdx.x, t = threadIdx.x;
  if (bx < 128) {
    int c = bx;
#pragma unroll
    for (int part = 0; part < 3; ++part) {
      int k = part * 128 + t;
      float v = (k < 128) ? w_in[(size_t)k * 128 + c] : G[(size_t)(k - 128) * 128 + c];
      wtP2[(size_t)c * 384 + k] = f2bf(v);
    }
  } else if (bx < 896) {
    int b2 = bx - 128;
    int l = b2 / 384, rem = b2 % 384, o = rem >> 7, c = rem & 127;
    const float* w = (o == 0 ? wq : (o == 1 ? wk : wv)) + (size_t)l * 16384;
    wt3[(size_t)b2 * 128 + t] = f2bf(w[(size_t)t * 128 + c]);
  } else {
    int c = (bx - 896) * 2 + (t >> 6), kk = t & 63;
    float s = (c < 64) ? 0.25f : 1.f;
    wtQK[(size_t)c * 64 + kk] = f2bf(s * in_w[(size_t)kk * 192 + c]);
  }
}

// ---------------------------------------------------------------------------
// k_mhafill: blocks 0..3749 = k_mha9 (fused QK-GEMM + attention + Y);
// blocks 3750..5629 = XCD-sliced adjacency fill (independent work, runs in
// the mha blocks' occupancy shadow - one launch instead of two).
// ---------------------------------------------------------------------------
#define MHAB 3750
#define FB2 235   // fill blocks per XCD group (512 thr); total 8*235 = 1880
__global__ __launch_bounds__(512) void k_mhafill(
    const float* __restrict__ xn, const u16* __restrict__ wtQK,
    const float* __restrict__ in_b, u16* __restrict__ Yb,
    const int* __restrict__ ei, int* __restrict__ cnt, int* __restrict__ esrc) {
  __shared__ unsigned qks[80 * 66];
  __shared__ float cs_lds[8][4][12];
  int t = threadIdx.x;

  if (blockIdx.x >= MHAB) {
    // ---- fill path ----
    int fb = blockIdx.x - MHAB;
    int grp = fb & 7, bi = fb >> 3;
    int lo = grp * (NN / 8), hi = lo + (NN / 8);
    int tid = bi * 512 + t;            // 0..120319
#pragma unroll
    for (int it = 0; it < 8; ++it) {
      int e = tid + it * (FB2 * 512);  // stride 120320, covers 962560 >= 2E
      if (e < 2 * EE) {
        int l = e >= EE;
        int ee = e - l * EE;
        int d = ei[(size_t)(2 * l + 1) * EE + ee];
        if (d >= lo && d < hi) {
          int s = ei[(size_t)(2 * l) * EE + ee];
          int c = atomicAdd(&cnt[l * NN + d], 1);
          if (c < 64) esrc[((size_t)l * NN + d) * 64 + c] = s;
        }
      }
    }
    return;
  }

  // ---- mha path (identical to k_mha9) ----
  int w = t >> 6, l = t & 63;
  int lr = l & 15, lq = l >> 4;
  const floatx4 zf = {0.f, 0.f, 0.f, 0.f};
  size_t r0 = (size_t)blockIdx.x * 80;

  if (w < 5) {
    int row = w * 16 + lr;
    size_t arow = r0 + row;
    const float* xp = xn + arow * 64 + lq * 8;
    float4 f0 = *(const float4*)xp;
    float4 f1 = *(const float4*)(xp + 4);
    float4 f2 = *(const float4*)(xp + 32);
    float4 f3 = *(const float4*)(xp + 36);
    short8 a0 = pack8(f0, f1), a1 = pack8(f2, f3);
    floatx4 acc[8];
#pragma unroll
    for (int ct = 0; ct < 8; ++ct) acc[ct] = zf;
#pragma unroll
    for (int ct = 0; ct < 8; ++ct) {
      const short8* bp = (const short8*)(wtQK + (size_t)(ct * 16 + lr) * 64);
      acc[ct] = MFMA32(a0, bp[lq], acc[ct], 0, 0, 0);
      acc[ct] = MFMA32(a1, bp[4 + lq], acc[ct], 0, 0, 0);
    }
#pragma unroll
    for (int ct = 0; ct < 4; ++ct) {
      float bq_ = in_b[ct * 16 + lr] * 0.25f;
      float bk_ = in_b[64 + ct * 16 + lr];
#pragma unroll
      for (int r = 0; r < 4; ++r)
        qks[(w * 16 + lq * 4 + r) * 66 + ct * 16 + lr] =
            packbf(acc[ct][r] + bq_, acc[ct + 4][r] + bk_);
    }
  }
  __syncthreads();

  int seqc = lr < 10 ? lr : 9;
  {
#pragma unroll
    for (int h = 0; h < 4; ++h) {
      const unsigned* rp = &qks[(w * 10 + seqc) * 66 + h * 16 + lq * 4];
      uint2 u0 = *(const uint2*)rp;
      uint2 u1 = *(const uint2*)(rp + 2);
      union { unsigned u[2]; short4v s; } qv, kv;
      qv.u[0] = (u0.x & 0xFFFFu) | (u0.y << 16);
      qv.u[1] = (u1.x & 0xFFFFu) | (u1.y << 16);
      kv.u[0] = (u0.x >> 16) | (u0.y & 0xFFFF0000u);
      kv.u[1] = (u1.x >> 16) | (u1.y & 0xFFFF0000u);
      floatx4 s4 = MFMA16(kv.s, qv.s, zf);   // S^T[j=lq*4+r][i=lr]
      int j0 = lq * 4;
      float e0 = (j0 + 0 < 10) ? __expf(s4[0]) : 0.f;
      float e1 = (j0 + 1 < 10) ? __expf(s4[1]) : 0.f;
      float e2 = (j0 + 2 < 10) ? __expf(s4[2]) : 0.f;
      float e3 = (j0 + 3 < 10) ? __expf(s4[3]) : 0.f;
      float den = e0 + e1 + e2 + e3;
      den += __shfl_xor(den, 16, 64);
      den += __shfl_xor(den, 32, 64);
      float rden = 0.1f / den;  // fold seq-mean 1/10
      float v0 = (lr < 10) ? e0 * rden : 0.f;
      float v1 = (lr < 10) ? e1 * rden : 0.f;
      float v2 = (lr < 10) ? e2 * rden : 0.f;
      float v3 = (lr < 10) ? e3 * rden : 0.f;
      v0 = rowsum16(v0);
      v1 = rowsum16(v1);
      v2 = rowsum16(v2);
      v3 = rowsum16(v3);
      if (lr == 0) {
        cs_lds[w][h][lq * 4 + 0] = v0;
        cs_lds[w][h][lq * 4 + 1] = v1;
        cs_lds[w][h][lq * 4 + 2] = v2;
        cs_lds[w][h][lq * 4 + 3] = v3;
      }
    }
    size_t node = (size_t)blockIdx.x * 8 + w;
    const float* xp2 = xn + node * 640 + l;  // lane l = dim d
    float y0 = 0.f, y1 = 0.f, y2 = 0.f, y3 = 0.f;
#pragma unroll
    for (int j = 0; j < 10; ++j) {
      float xv = xp2[j * 64];                // coalesced 256B, cache-warm
      y0 = fmaf(cs_lds[w][0][j], xv, y0);
      y1 = fmaf(cs_lds[w][1][j], xv, y1);
      y2 = fmaf(cs_lds[w][2][j], xv, y2);
      y3 = fmaf(cs_lds[w][3][j], xv, y3);
    }
    size_t yb = node * 256;
    Yb[yb + l] = f2bf(y0);
    Yb[yb + 64 + l] = f2bf(y1);
    Yb[yb + 128 + l] = f2bf(y2);
    Yb[yb + 192 + l] = f2bf(y3);
  }
}

// ---------------------------------------------------------------------------
// k_projqkv4: layer-0 proj+QKV, 64 rows/block, 512 thr, B-frag prefetch.
// ---------------------------------------------------------------------------
__global__ __launch_bounds__(512) void k_projqkv4(
    const float* __restrict__ x, const u16* __restrict__ Yb,
    const u16* __restrict__ wtP2, const float* __restrict__ fusedB2,
    const u16* __restrict__ wt3l,
    const float* __restrict__ bqL, const float* __restrict__ bkL,
    const float* __restrict__ bvL,
    unsigned* __restrict__ q2, unsigned* __restrict__ k2, unsigned* __restrict__ v2) {
  __shared__ u16 hs[64 * 128];
  int t = threadIdx.x, w = t >> 6, l = t & 63, lr = l & 15, lq = l >> 4;
  int wr = w & 3, half = w >> 2;
  int row0 = blockIdx.x * 64 + wr * 16;
  int arow = row0 + lr; if (arow >= NN) arow = NN - 1;
  {
    const float* xp = x + (size_t)arow * 128;
    const short8* yp = (const short8*)(Yb + (size_t)arow * 256);
    short8 afr[12];
#pragma unroll
    for (int kb = 0; kb < 4; ++kb) {
      float4 fa = *(const float4*)(xp + kb * 32 + lq * 8);
      float4 fb = *(const float4*)(xp + kb * 32 + lq * 8 + 4);
      afr[kb] = pack8(fa, fb);
    }
#pragma unroll
    for (int m = 0; m < 8; ++m) afr[4 + m] = yp[m * 4 + lq];
    floatx4 acc[4];
#pragma unroll
    for (int ct = 0; ct < 4; ++ct) acc[ct] = (floatx4){0.f, 0.f, 0.f, 0.f};
#pragma unroll
    for (int ct = 0; ct < 4; ++ct) {
      int ctg = half * 4 + ct;
      const short8* bp = (const short8*)(wtP2 + (size_t)(ctg * 16 + lr) * 384);
      short8 bfr[12];
#pragma unroll
      for (int kb = 0; kb < 12; ++kb) bfr[kb] = bp[kb * 4 + lq];
#pragma unroll
      for (int kb = 0; kb < 12; ++kb)
        acc[ct] = MFMA32(afr[kb], bfr[kb], acc[ct], 0, 0, 0);
    }
#pragma unroll
    for (int ct = 0; ct < 4; ++ct) {
      int ctg = half * 4 + ct;
      int col = ctg * 16 + lr;
      float bias = fusedB2[col];
#pragma unroll
      for (int r = 0; r < 4; ++r)
        hs[(wr * 16 + lq * 4 + r) * 128 + col] = f2bf(acc[ct][r] + bias);
    }
  }
  __syncthreads();
  {
    int lrow = wr * 16 + lr;
    const short8* ap = (const short8*)(hs + lrow * 128);
    short8 a0 = ap[lq], a1 = ap[4 + lq], a2 = ap[8 + lq], a3 = ap[12 + lq];
    const short8* wt8 = (const short8*)wt3l;
    floatx4 accL[6], accH[6];
#pragma unroll
    for (int p = 0; p < 6; ++p) {
      accL[p] = (floatx4){0.f, 0.f, 0.f, 0.f};
      accH[p] = (floatx4){0.f, 0.f, 0.f, 0.f};
    }
#pragma unroll
    for (int p = 0; p < 6; ++p) {
      int pg = half * 6 + p;
      int o = pg >> 2, cc = pg & 3;
      const short8* bpL = wt8 + (size_t)(o * 128 + cc * 16 + lr) * 16;
      const short8* bpH = wt8 + (size_t)(o * 128 + (cc + 4) * 16 + lr) * 16;
      short8 bl[4], bh[4];
#pragma unroll
      for (int kb = 0; kb < 4; ++kb) { bl[kb] = bpL[kb * 4 + lq]; bh[kb] = bpH[kb * 4 + lq]; }
      accL[p] = MFMA32(a0, bl[0], accL[p], 0, 0, 0);
      accL[p] = MFMA32(a1, bl[1], accL[p], 0, 0, 0);
      accL[p] = MFMA32(a2, bl[2], accL[p], 0, 0, 0);
      accL[p] = MFMA32(a3, bl[3], accL[p], 0, 0, 0);
      accH[p] = MFMA32(a0, bh[0], accH[p], 0, 0, 0);
      accH[p] = MFMA32(a1, bh[1], accH[p], 0, 0, 0);
      accH[p] = MFMA32(a2, bh[2], accH[p], 0, 0, 0);
      accH[p] = MFMA32(a3, bh[3], accH[p], 0, 0, 0);
    }
#pragma unroll
    for (int p = 0; p < 6; ++p) {
      int pg = half * 6 + p;
      int o = pg >> 2, cc = pg & 3;
      unsigned* op = o == 0 ? q2 : (o == 1 ? k2 : v2);
      const float* bp2 = o == 0 ? bqL : (o == 1 ? bkL : bvL);
      int col = cc * 16 + lr;
      float blo = bp2[col], bhi = bp2[64 + col];
#pragma unroll
      for (int r = 0; r < 4; ++r) {
        int row = row0 + lq * 4 + r;
        if (row < NN)
          op[(size_t)row * 64 + col] = packbf(accL[p][r] + blo, accH[p][r] + bhi);
      }
    }
  }
}

// ---------------------------------------------------------------------------
// k_qkv4d: layer-1 QKV, 64 rows/block, 512 thr, B-frag prefetch.
// ---------------------------------------------------------------------------
__global__ __launch_bounds__(512) void k_qkv4d(
    const u16* __restrict__ hb, const u16* __restrict__ wt3l,
    const float* __restrict__ bqL, const float* __restrict__ bkL,
    const float* __restrict__ bvL,
    unsigned* __restrict__ q2, unsigned* __restrict__ k2, unsigned* __restrict__ v2) {
  int t = threadIdx.x, w = t >> 6, l = t & 63, lr = l & 15, lq = l >> 4;
  int wr = w & 3, half = w >> 2;
  int row0 = blockIdx.x * 64 + wr * 16;
  int arow = row0 + lr; if (arow >= NN) arow = NN - 1;
  const short8* ap = (const short8*)(hb + (size_t)arow * 128);
  short8 a0 = ap[lq], a1 = ap[4 + lq], a2 = ap[8 + lq], a3 = ap[12 + lq];
  const short8* wt8 = (const short8*)wt3l;
  floatx4 accL[6], accH[6];
#pragma unroll
  for (int p = 0; p < 6; ++p) {
    accL[p] = (floatx4){0.f, 0.f, 0.f, 0.f};
    accH[p] = (floatx4){0.f, 0.f, 0.f, 0.f};
  }
#pragma unroll
  for (int p = 0; p < 6; ++p) {
    int pg = half * 6 + p;
    int o = pg >> 2, cc = pg & 3;
    const short8* bpL = wt8 + (size_t)(o * 128 + cc * 16 + lr) * 16;
    const short8* bpH = wt8 + (size_t)(o * 128 + (cc + 4) * 16 + lr) * 16;
    short8 bl[4], bh[4];
#pragma unroll
    for (int kb = 0; kb < 4; ++kb) { bl[kb] = bpL[kb * 4 + lq]; bh[kb] = bpH[kb * 4 + lq]; }
    accL[p] = MFMA32(a0, bl[0], accL[p], 0, 0, 0);
    accL[p] = MFMA32(a1, bl[1], accL[p], 0, 0, 0);
    accL[p] = MFMA32(a2, bl[2], accL[p], 0, 0, 0);
    accL[p] = MFMA32(a3, bl[3], accL[p], 0, 0, 0);
    accH[p] = MFMA32(a0, bh[0], accH[p], 0, 0, 0);
    accH[p] = MFMA32(a1, bh[1], accH[p], 0, 0, 0);
    accH[p] = MFMA32(a2, bh[2], accH[p], 0, 0, 0);
    accH[p] = MFMA32(a3, bh[3], accH[p], 0, 0, 0);
  }
#pragma unroll
  for (int p = 0; p < 6; ++p) {
    int pg = half * 6 + p;
    int o = pg >> 2, cc = pg & 3;
    unsigned* op = o == 0 ? q2 : (o == 1 ? k2 : v2);
    const float* bp2 = o == 0 ? bqL : (o == 1 ? bkL : bvL);
    int col = cc * 16 + lr;
    float blo = bp2[col], bhi = bp2[64 + col];
#pragma unroll
    for (int r = 0; r < 4; ++r) {
      int row = row0 + lq * 4 + r;
      if (row < NN)
        op[(size_t)row * 64 + col] = packbf(accL[p][r] + blo, accH[p][r] + bhi);
    }
  }
}

// ---------------------------------------------------------------------------
// k_sagg7: fused edge-score + segment-softmax (no max) + PV + ReLU + LN.
// ---------------------------------------------------------------------------
__global__ __launch_bounds__(256) void k_sagg7(
    const unsigned* __restrict__ q2, const unsigned* __restrict__ k2,
    const unsigned* __restrict__ v2, const int* __restrict__ esrc,
    const int* __restrict__ cnt, const float* __restrict__ g,
    const float* __restrict__ bb, u16* __restrict__ hb,
    const float* __restrict__ wo, const float* __restrict__ bo,
    float* __restrict__ outp) {
  const float SC = 0.17677669529663687f;
  int t = threadIdx.x, w = t >> 6, l = t & 63;
  int e = l >> 4, dd = l & 15;
  int n = blockIdx.x * 4 + w;
  int deg = cnt[n]; if (deg > 64) deg = 64;
  const int* sp = esrc + (size_t)n * 64;
  uint4 qp = *(const uint4*)(q2 + (size_t)n * 64 + dd * 4);
  float ql0 = bflo(qp.x), ql1 = bflo(qp.y), ql2 = bflo(qp.z), ql3 = bflo(qp.w);
  float qh0 = bfhi(qp.x), qh1 = bfhi(qp.y), qh2 = bfhi(qp.z), qh3 = bfhi(qp.w);
  float dA0 = 0.f, dA1 = 0.f, dB0 = 0.f, dB1 = 0.f;
  float alA0 = 0.f, alA1 = 0.f, alA2 = 0.f, alA3 = 0.f;
  float ahA0 = 0.f, ahA1 = 0.f, ahA2 = 0.f, ahA3 = 0.f;
  float alB0 = 0.f, alB1 = 0.f, alB2 = 0.f, alB3 = 0.f;
  float ahB0 = 0.f, ahB1 = 0.f, ahB2 = 0.f, ahB3 = 0.f;
  uint4 kA = {0, 0, 0, 0}, vA = {0, 0, 0, 0};
  uint4 kB = {0, 0, 0, 0}, vB = {0, 0, 0, 0};
  bool mA = false, mB = false;
  if (deg > 0) {
    int iA = e < deg ? e : deg - 1;           mA = e < deg;
    int iB = 4 + e < deg ? 4 + e : deg - 1;   mB = 4 + e < deg;
    int sA = sp[iA], sB = sp[iB];
    kA = *(const uint4*)(k2 + (size_t)sA * 64 + dd * 4);
    vA = *(const uint4*)(v2 + (size_t)sA * 64 + dd * 4);
    kB = *(const uint4*)(k2 + (size_t)sB * 64 + dd * 4);
    vB = *(const uint4*)(v2 + (size_t)sB * 64 + dd * 4);
  }
  for (int base = 0; base < deg; base += 8) {
    uint4 kAn = {0, 0, 0, 0}, vAn = {0, 0, 0, 0};
    uint4 kBn = {0, 0, 0, 0}, vBn = {0, 0, 0, 0};
    bool mAn = false, mBn = false;
    int nb = base + 8;
    if (nb < deg) {
      int iA = nb + e < deg ? nb + e : deg - 1;         mAn = nb + e < deg;
      int iB = nb + 4 + e < deg ? nb + 4 + e : deg - 1; mBn = nb + 4 + e < deg;
      int sA = sp[iA], sB = sp[iB];
      kAn = *(const uint4*)(k2 + (size_t)sA * 64 + dd * 4);
      vAn = *(const uint4*)(v2 + (size_t)sA * 64 + dd * 4);
      kBn = *(const uint4*)(k2 + (size_t)sB * 64 + dd * 4);
      vBn = *(const uint4*)(v2 + (size_t)sB * 64 + dd * 4);
    }
    float rA0 = ql0 * bflo(kA.x) + ql1 * bflo(kA.y) + ql2 * bflo(kA.z) + ql3 * bflo(kA.w);
    float rA1 = qh0 * bfhi(kA.x) + qh1 * bfhi(kA.y) + qh2 * bfhi(kA.z) + qh3 * bfhi(kA.w);
    float rB0 = ql0 * bflo(kB.x) + ql1 * bflo(kB.y) + ql2 * bflo(kB.z) + ql3 * bflo(kB.w);
    float rB1 = qh0 * bfhi(kB.x) + qh1 * bfhi(kB.y) + qh2 * bfhi(kB.z) + qh3 * bfhi(kB.w);
    rA0 = rowsum8(rA0); rA1 = rowsum8(rA1);
    rB0 = rowsum8(rB0); rB1 = rowsum8(rB1);
    float pA0 = mA ? __expf(rA0 * SC) : 0.f;
    float pA1 = mA ? __expf(rA1 * SC) : 0.f;
    float pB0 = mB ? __expf(rB0 * SC) : 0.f;
    float pB1 = mB ? __expf(rB1 * SC) : 0.f;
    dA0 += pA0; dA1 += pA1; dB0 += pB0; dB1 += pB1;
    alA0 = fmaf(pA0, bflo(vA.x), alA0); alA1 = fmaf(pA0, bflo(vA.y), alA1);
    alA2 = fmaf(pA0, bflo(vA.z), alA2); alA3 = fmaf(pA0, bflo(vA.w), alA3);
    ahA0 = fmaf(pA1, bfhi(vA.x), ahA0); ahA1 = fmaf(pA1, bfhi(vA.y), ahA1);
    ahA2 = fmaf(pA1, bfhi(vA.z), ahA2); ahA3 = fmaf(pA1, bfhi(vA.w), ahA3);
    alB0 = fmaf(pB0, bflo(vB.x), alB0); alB1 = fmaf(pB0, bflo(vB.y), alB1);
    alB2 = fmaf(pB0, bflo(vB.z), alB2); alB3 = fmaf(pB0, bflo(vB.w), alB3);
    ahB0 = fmaf(pB1, bfhi(vB.x), ahB0); ahB1 = fmaf(pB1, bfhi(vB.y), ahB1);
    ahB2 = fmaf(pB1, bfhi(vB.z), ahB2); ahB3 = fmaf(pB1, bfhi(vB.w), ahB3);
    kA = kAn; vA = vAn; mA = mAn;
    kB = kBn; vB = vBn; mB = mBn;
  }
  float d0 = dA0 + dB0, d1 = dA1 + dB1;
  float al0 = alA0 + alB0, al1 = alA1 + alB1, al2 = alA2 + alB2, al3 = alA3 + alB3;
  float ah0 = ahA0 + ahB0, ah1 = ahA1 + ahB1, ah2 = ahA2 + ahB2, ah3 = ahA3 + ahB3;
  d0 += __shfl_xor(d0, 16, 64); d0 += __shfl_xor(d0, 32, 64);
  d1 += __shfl_xor(d1, 16, 64); d1 += __shfl_xor(d1, 32, 64);
  al0 += __shfl_xor(al0, 16, 64); al0 += __shfl_xor(al0, 32, 64);
  al1 += __shfl_xor(al1, 16, 64); al1 += __shfl_xor(al1, 32, 64);
  al2 += __shfl_xor(al2, 16, 64); al2 += __shfl_xor(al2, 32, 64);
  al3 += __shfl_xor(al3, 16, 64); al3 += __shfl_xor(al3, 32, 64);
  ah0 += __shfl_xor(ah0, 16, 64); ah0 += __shfl_xor(ah0, 32, 64);
  ah1 += __shfl_xor(ah1, 16, 64); ah1 += __shfl_xor(ah1, 32, 64);
  ah2 += __shfl_xor(ah2, 16, 64); ah2 += __shfl_xor(ah2, 32, 64);
  ah3 += __shfl_xor(ah3, 16, 64); ah3 += __shfl_xor(ah3, 32, 64);
  float rd0 = 1.f / fmaxf(d0, 1e-9f), rd1 = 1.f / fmaxf(d1, 1e-9f);
  float ol0 = fmaxf(al0 * rd0, 0.f), ol1 = fmaxf(al1 * rd0, 0.f);
  float ol2 = fmaxf(al2 * rd0, 0.f), ol3 = fmaxf(al3 * rd0, 0.f);
  float oh0 = fmaxf(ah0 * rd1, 0.f), oh1 = fmaxf(ah1 * rd1, 0.f);
  float oh2 = fmaxf(ah2 * rd1, 0.f), oh3 = fmaxf(ah3 * rd1, 0.f);
  float s1 = ol0 + ol1 + ol2 + ol3 + oh0 + oh1 + oh2 + oh3;
  float s2 = ol0 * ol0 + ol1 * ol1 + ol2 * ol2 + ol3 * ol3 +
             oh0 * oh0 + oh1 * oh1 + oh2 * oh2 + oh3 * oh3;
  s1 = rowsum16(s1);
  s2 = rowsum16(s2);
  float mean = s1 * (1.f / 128.f);
  float var = s2 * (1.f / 128.f) - mean * mean;
  float rs = rsqrtf(var + 1e-5f);
  if (e == 0) {
    floatx4 gl = *(const floatx4*)(g + dd * 4);
    floatx4 bl = *(const floatx4*)(bb + dd * 4);
    floatx4 gh = *(const floatx4*)(g + 64 + dd * 4);
    floatx4 bh = *(const floatx4*)(bb + 64 + dd * 4);
    float hl0 = (ol0 - mean) * rs * gl[0] + bl[0];
    float hl1 = (ol1 - mean) * rs * gl[1] + bl[1];
    float hl2 = (ol2 - mean) * rs * gl[2] + bl[2];
    float hl3 = (ol3 - mean) * rs * gl[3] + bl[3];
    float hh0 = (oh0 - mean) * rs * gh[0] + bh[0];
    float hh1 = (oh1 - mean) * rs * gh[1] + bh[1];
    float hh2 = (oh2 - mean) * rs * gh[2] + bh[2];
    float hh3 = (oh3 - mean) * rs * gh[3] + bh[3];
    if (outp == nullptr) {
      uint2 w0, w1;
      w0.x = packbf(hl0, hl1); w0.y = packbf(hl2, hl3);
      w1.x = packbf(hh0, hh1); w1.y = packbf(hh2, hh3);
      *(uint2*)(hb + (size_t)n * 128 + dd * 4) = w0;
      *(uint2*)(hb + (size_t)n * 128 + 64 + dd * 4) = w1;
    } else {
      const float2* wo2 = (const float2*)wo;
      float2 wa0 = wo2[dd * 4], wa1 = wo2[dd * 4 + 1];
      float2 wa2 = wo2[dd * 4 + 2], wa3 = wo2[dd * 4 + 3];
      float2 wb0 = wo2[64 + dd * 4], wb1 = wo2[64 + dd * 4 + 1];
      float2 wb2 = wo2[64 + dd * 4 + 2], wb3 = wo2[64 + dd * 4 + 3];
      float p0 = hl0 * wa0.x + hl1 * wa1.x + hl2 * wa2.x + hl3 * wa3.x +
                 hh0 * wb0.x + hh1 * wb1.x + hh2 * wb2.x + hh3 * wb3.x;
      float p1 = hl0 * wa0.y + hl1 * wa1.y + hl2 * wa2.y + hl3 * wa3.y +
                 hh0 * wb0.y + hh1 * wb1.y + hh2 * wb2.y + hh3 * wb3.y;
      p0 = rowsum16(p0);
      p1 = rowsum16(p1);
      if (dd == 0) {
        outp[n * 2] = p0 + bo[0];
        outp[n * 2 + 1] = p1 + bo[1];
      }
    }
  }
}

// ---------------------------------------------------------------------------
extern "C" void kernel_launch(void* const* d_in, const int* in_sizes, int n_in,
                              void* d_out, int out_size, void* d_ws, size_t ws_size,
                              hipStream_t stream) {
  const float* x = (const float*)d_in[0];
  const float* neif = (const float*)d_in[1];
  const int* ei = (const int*)d_in[2];
  const float* w_in = (const float*)d_in[3];
  const float* b_in = (const float*)d_in[4];
  const float* mha_in_w = (const float*)d_in[5];
  const float* mha_in_b = (const float*)d_in[6];
  const float* mha_out_w = (const float*)d_in[7];
  const float* mha_out_b = (const float*)d_in[8];
  const float* w_nei = (const float*)d_in[9];
  const float* b_nei = (const float*)d_in[10];
  const float* wq = (const float*)d_in[11];
  const float* bq = (const float*)d_in[12];
  const float* wk = (const float*)d_in[13];
  const float* bk = (const float*)d_in[14];
  const float* wv = (const float*)d_in[15];
  const float* bv = (const float*)d_in[16];
  const float* ln_g = (const float*)d_in[17];
  const float* ln_b = (const float*)d_in[18];
  const float* w_out = (const float*)d_in[19];
  const float* b_out = (const float*)d_in[20];
  float* out = (float*)d_out;

  // workspace layout (~62 MB)
  char* wsb = (char*)d_ws;
  size_t off = 0;
  unsigned* q2 = (unsigned*)(wsb + off); off += (size_t)NN * 64 * 4;
  unsigned* k2 = (unsigned*)(wsb + off); off += (size_t)NN * 64 * 4;
  unsigned* v2 = (unsigned*)(wsb + off); off += (size_t)NN * 64 * 4;
  int* esrc = (int*)(wsb + off);         off += (size_t)2 * NN * 64 * 4;
  int* cnt = (int*)(wsb + off);          off += (size_t)2 * NN * 4;
  u16* Yb = (u16*)(wsb + off);           off += (size_t)NN * 256 * 2;
  u16* hb = (u16*)(wsb + off);           off += (size_t)NN * 128 * 2;
  u16* wt3 = (u16*)(wsb + off);          off += (size_t)768 * 128 * 2;
  u16* wtP2 = (u16*)(wsb + off);         off += (size_t)128 * 384 * 2;
  u16* wtQK = (u16*)(wsb + off);         off += (size_t)128 * 64 * 2;
  float* G = (float*)(wsb + off);        off += (size_t)256 * 128 * 4;
  float* fusedW = (float*)(wsb + off);   off += 64 * 128 * 4;
  float* fusedB = (float*)(wsb + off);   off += 128 * 4;
  float* fusedB2 = (float*)(wsb + off);  off += 128 * 4;

  hipMemsetAsync(cnt, 0, (size_t)2 * NN * sizeof(int), stream);
  k_fuse<<<65, 128, 0, stream>>>(mha_out_w, mha_out_b, w_nei, b_nei, b_in, fusedW, fusedB);
  k_prepB<<<257, 128, 0, stream>>>(mha_in_w, fusedW, fusedB, mha_in_b, G, fusedB2);
  k_prep2<<<960, 128, 0, stream>>>(w_in, G, wq, wk, wv, mha_in_w, wtP2, wt3, wtQK);

  // mha + adjacency fill in one launch (independent block ranges)
  k_mhafill<<<MHAB + 8 * FB2, 512, 0, stream>>>(neif, wtQK, mha_in_b, Yb,
                                                ei, cnt, esrc);

  // layer 0: proj + qkv fused (h0 stays in LDS)
  k_projqkv4<<<469, 512, 0, stream>>>(x, Yb, wtP2, fusedB2, wt3,
                                      bq, bk, bv, q2, k2, v2);
  k_sagg7<<<NN / 4, 256, 0, stream>>>(q2, k2, v2, esrc, cnt,
                                      ln_g, ln_b, hb, w_out, b_out, nullptr);
  // layer 1
  k_qkv4d<<<469, 512, 0, stream>>>(hb, wt3 + (size_t)3 * 128 * 128,
                                   bq + 128, bk + 128, bv + 128, q2, k2, v2);
  k_sagg7<<<NN / 4, 256, 0, stream>>>(q2, k2, v2, esrc + (size_t)NN * 64,
                                      cnt + NN, ln_g + 128, ln_b + 128, hb,
                                      w_out, b_out, out);
}